// Round 2
// baseline (609.781 us; speedup 1.0000x reference)
//
#include <hip/hip_runtime.h>

typedef __bf16 bf16x8 __attribute__((ext_vector_type(8)));
typedef float f32x4 __attribute__((ext_vector_type(4)));
typedef unsigned short u16;
typedef unsigned int u32;
typedef u16 u16x8 __attribute__((ext_vector_type(8)));
typedef u16 u16x4 __attribute__((ext_vector_type(4)));

// ---------- constants ----------
// B=16, SV=1024, ST=512, D=768, H=8, DH=96
// Processing is chunked over batches: CH batches per chunk, R = CH*1536 local rows
// (first CH*1024 visual, then CH*512 text).

__device__ __forceinline__ u16 f2bf(float f) {
    u32 u = __builtin_bit_cast(u32, f);
    u32 r = u + 0x7FFFu + ((u >> 16) & 1u);
    return (u16)(r >> 16);
}

__device__ __forceinline__ f32x4 mfma16(bf16x8 a, bf16x8 b, f32x4 c) {
    return __builtin_amdgcn_mfma_f32_16x16x32_bf16(a, b, c, 0, 0, 0);
}

#define GLOAD_LDS16(g, l) __builtin_amdgcn_global_load_lds( \
    (__attribute__((address_space(1))) void*)(g), \
    (__attribute__((address_space(3))) void*)(l), 16, 0, 0)

// ---------- prep kernels ----------

// concat+convert chunk tokens: X[0:CH*1024) = visual, X[CH*1024:CH*1536) = text (bf16)
__global__ __launch_bounds__(256) void k_cvt_x(const float* __restrict__ vf,
                                               const float* __restrict__ tf,
                                               u16* __restrict__ X, int nvis4) {
    int i = blockIdx.x * 256 + threadIdx.x;  // one float4 per thread
    f32x4 v = (i < nvis4) ? ((const f32x4*)vf)[i] : ((const f32x4*)tf)[i - nvis4];
    u16x4 o = { f2bf(v[0]), f2bf(v[1]), f2bf(v[2]), f2bf(v[3]) };
    ((u16x4*)X)[i] = o;
}

// src f32 [K0][N0] -> dst bf16 [N0][K0]   (64x64 LDS tiles)
__global__ __launch_bounds__(256) void k_transpose(const float* __restrict__ src,
                                                   u16* __restrict__ dst,
                                                   int K0, int N0) {
    __shared__ float t[64][65];
    int ntx = N0 >> 6;
    int k0 = (blockIdx.x / ntx) << 6, n0 = (blockIdx.x % ntx) << 6;
    int c = threadIdx.x & 63, rr = threadIdx.x >> 6;
#pragma unroll
    for (int q = 0; q < 16; q++) {
        int r = q * 4 + rr;
        t[r][c] = src[(size_t)(k0 + r) * N0 + n0 + c];
    }
    __syncthreads();
#pragma unroll
    for (int q = 0; q < 16; q++) {
        int r = q * 4 + rr;
        dst[(size_t)(n0 + r) * K0 + k0 + c] = f2bf(t[c][r]);
    }
}

__global__ __launch_bounds__(256) void k_bias(const float* __restrict__ bq,
                                              const float* __restrict__ bk,
                                              const float* __restrict__ bv,
                                              float* __restrict__ bqkv) {
    int n = blockIdx.x * 256 + threadIdx.x;
    if (n < 2304) {
        const float* s = (n < 768) ? bq : ((n < 1536) ? bk : bv);
        int r = (n < 768) ? n : ((n < 1536) ? n - 768 : n - 1536);
        bqkv[n] = s[r];
    }
}

__global__ __launch_bounds__(256) void k_zero(float* __restrict__ p) {
    p[blockIdx.x * 256 + threadIdx.x] = 0.f;
}

// ---------- GEMM: C[R][N] = A[R][K] * Bt[N][K]^T + bias (+residual) ----------
// m97-style: 128x128 tile, BK=32, 4 waves (2x2), global_load_lds width 16.
// ADD_RES only used with Ndim==768 (residual row stride 768).
template <bool OUT_BF16, bool ADD_RES>
__global__ __launch_bounds__(256) void k_gemm(const u16* __restrict__ A,
                                              const u16* __restrict__ Bt,
                                              const float* __restrict__ bias,
                                              const float* __restrict__ resA,
                                              const float* __restrict__ resB,
                                              void* __restrict__ Cout,
                                              int Ndim, int Kdim, int mvisL) {
    __shared__ alignas(16) u16 sA[128 * 32];
    __shared__ alignas(16) u16 sB[128 * 32];
    const int tid = threadIdx.x, wid = tid >> 6, lane = tid & 63;
    const int ntiles = Ndim >> 7;
    const int mt = blockIdx.x / ntiles, nt = blockIdx.x - mt * ntiles;
    const int m0 = mt << 7, n0 = nt << 7;
    const int wm = wid >> 1, wn = wid & 1;
    f32x4 acc[4][4] = {};

    const int r0 = tid >> 2, p0 = tid & 3;
    const int r1 = 64 + (tid >> 2);
    const u16* ga0 = A + (size_t)(m0 + r0) * Kdim + p0 * 8;
    const u16* ga1 = A + (size_t)(m0 + r1) * Kdim + p0 * 8;
    const u16* gb0 = Bt + (size_t)(n0 + r0) * Kdim + p0 * 8;
    const u16* gb1 = Bt + (size_t)(n0 + r1) * Kdim + p0 * 8;
    u16* lA0 = sA + (wid * 64) * 8;
    u16* lA1 = sA + (256 + wid * 64) * 8;
    u16* lB0 = sB + (wid * 64) * 8;
    u16* lB1 = sB + (256 + wid * 64) * 8;

    const int arow = (wm << 6) + (lane & 15);
    const int brow = (wn << 6) + (lane & 15);
    const int kg = (lane >> 4) * 8;

    for (int kt = 0; kt < Kdim; kt += 32) {
        GLOAD_LDS16(ga0 + kt, lA0);
        GLOAD_LDS16(ga1 + kt, lA1);
        GLOAD_LDS16(gb0 + kt, lB0);
        GLOAD_LDS16(gb1 + kt, lB1);
        __syncthreads();
        bf16x8 av[4], bw[4];
#pragma unroll
        for (int i = 0; i < 4; i++) av[i] = *(const bf16x8*)&sA[(arow + i * 16) * 32 + kg];
#pragma unroll
        for (int j = 0; j < 4; j++) bw[j] = *(const bf16x8*)&sB[(brow + j * 16) * 32 + kg];
#pragma unroll
        for (int i = 0; i < 4; i++)
#pragma unroll
            for (int j = 0; j < 4; j++) acc[i][j] = mfma16(av[i], bw[j], acc[i][j]);
        __syncthreads();
    }

    // epilogue: C row = m0+wm*64+i*16+(lane>>4)*4+reg, col = n0+wn*64+j*16+(lane&15)
    const int col0 = n0 + (wn << 6) + (lane & 15);
    const int rowb = m0 + (wm << 6) + ((lane >> 4) << 2);
    float bvals[4];
#pragma unroll
    for (int j = 0; j < 4; j++) bvals[j] = bias[col0 + j * 16];
#pragma unroll
    for (int i = 0; i < 4; i++) {
#pragma unroll
        for (int rg = 0; rg < 4; rg++) {
            const int row = rowb + i * 16 + rg;
            const float* rp = nullptr;
            if constexpr (ADD_RES)
                rp = (row < mvisL) ? resA + (size_t)row * 768
                                   : resB + (size_t)(row - mvisL) * 768;
#pragma unroll
            for (int j = 0; j < 4; j++) {
                const int col = col0 + j * 16;
                float v = acc[i][j][rg] + bvals[j];
                if constexpr (ADD_RES) v += rp[col];
                if constexpr (OUT_BF16)
                    ((u16*)Cout)[(size_t)row * Ndim + col] = f2bf(v);
                else
                    ((float*)Cout)[(size_t)row * Ndim + col] = v;
            }
        }
    }
}

// ---------- fused cross-attention (both directions), one chunk ----------
// qkv bf16 [R][2304] (Q|K|V). Block: 64 q-rows, 4 waves x 16 rows; K-tiles of 128.
__global__ __launch_bounds__(256) void k_attn(const u16* __restrict__ qkv,
                                              const int* __restrict__ vmaskc,
                                              const int* __restrict__ tmaskc,
                                              u16* __restrict__ attn, int CHn) {
    __shared__ alignas(16) u16 Kl[128 * 104];   // K tile, padded stride 104
    __shared__ alignas(16) u16 Vt[96 * 136];    // V^T tile [dh][k], padded stride 136
    __shared__ alignas(16) u16 Pl[4][16 * 136]; // per-wave P, padded stride 136
    __shared__ float mk[128];

    int bx = blockIdx.x;
    int b, h, qblk, Sk, qbase, kbase;
    const int* mask;
    const int vcap = CHn << 7;
    if (bx < vcap) {  // visual queries attend to text
        qblk = bx & 15; h = (bx >> 4) & 7; b = bx >> 7;
        qbase = b << 10; kbase = (CHn << 10) + (b << 9); Sk = 512; mask = tmaskc + (b << 9);
    } else {          // text queries attend to visual
        int bx2 = bx - vcap;
        qblk = bx2 & 7; h = (bx2 >> 3) & 7; b = bx2 >> 6;
        qbase = (CHn << 10) + (b << 9); kbase = b << 10; Sk = 1024; mask = vmaskc + (b << 10);
    }
    const int tid = threadIdx.x, wid = tid >> 6, lane = tid & 63;
    const int l15 = lane & 15, l4 = lane >> 4;

    // Q fragments (A-layout): row = lane&15, k = (lane>>4)*8 + e (+32*kk)
    const int qr = qbase + (qblk << 6) + (wid << 4) + l15;
    bf16x8 aq[3];
#pragma unroll
    for (int kk = 0; kk < 3; kk++)
        aq[kk] = *(const bf16x8*)&qkv[(size_t)qr * 2304 + h * 96 + kk * 32 + l4 * 8];

    f32x4 o[6] = {};
    float mrun[4] = {-1e30f, -1e30f, -1e30f, -1e30f};
    float lrun[4] = {0.f, 0.f, 0.f, 0.f};
    const float scale = 0.10206207261596577f;  // 1/sqrt(96)
    const int ntile = Sk >> 7;

    for (int t = 0; t < ntile; ++t) {
        __syncthreads();
        // stage K tile [128][96] and V^T tile [96][128]
#pragma unroll
        for (int it = 0; it < 6; ++it) {
            int c = it * 256 + tid;        // 1536 chunks of 8 bf16
            int r = c / 12, cc = c - r * 12;
            const u16* gp = qkv + (size_t)(kbase + (t << 7) + r) * 2304 + 768 + h * 96 + cc * 8;
            u16x8 kv = *(const u16x8*)gp;
            *(u16x8*)&Kl[r * 104 + cc * 8] = kv;
            u16x8 vv = *(const u16x8*)(gp + 768);
#pragma unroll
            for (int jj = 0; jj < 8; jj++) Vt[(cc * 8 + jj) * 136 + r] = vv[jj];
        }
        if (tid < 128) mk[tid] = (float)mask[(t << 7) + tid];
        __syncthreads();

        // S = Q K^T  (8 n-frags of 16 cols)
        f32x4 s[8];
#pragma unroll
        for (int j = 0; j < 8; j++) {
            f32x4 cj = {0.f, 0.f, 0.f, 0.f};
#pragma unroll
            for (int kk = 0; kk < 3; kk++) {
                bf16x8 bk8 = *(const bf16x8*)&Kl[(j * 16 + l15) * 104 + kk * 32 + l4 * 8];
                cj = mfma16(aq[kk], bk8, cj);
            }
            s[j] = cj;
        }
        // scale + mask + row max (row = l4*4+rg)
        float tmax[4] = {-1e30f, -1e30f, -1e30f, -1e30f};
#pragma unroll
        for (int j = 0; j < 8; j++) {
            float msk = mk[j * 16 + l15];
#pragma unroll
            for (int rg = 0; rg < 4; rg++) {
                float v = s[j][rg] * scale;
                v = (msk != 0.f) ? v : -1e30f;
                s[j][rg] = v;
                tmax[rg] = fmaxf(tmax[rg], v);
            }
        }
#pragma unroll
        for (int d = 1; d < 16; d <<= 1)
#pragma unroll
            for (int rg = 0; rg < 4; rg++) tmax[rg] = fmaxf(tmax[rg], __shfl_xor(tmax[rg], d));
        float corr[4], tsum[4];
#pragma unroll
        for (int rg = 0; rg < 4; rg++) {
            float mn = fmaxf(mrun[rg], tmax[rg]);
            corr[rg] = __expf(mrun[rg] - mn);
            mrun[rg] = mn;
            tsum[rg] = 0.f;
        }
#pragma unroll
        for (int j = 0; j < 8; j++)
#pragma unroll
            for (int rg = 0; rg < 4; rg++) {
                float p = __expf(s[j][rg] - mrun[rg]);
                tsum[rg] += p;
                Pl[wid][(l4 * 4 + rg) * 136 + j * 16 + l15] = f2bf(p);
            }
#pragma unroll
        for (int d = 1; d < 16; d <<= 1)
#pragma unroll
            for (int rg = 0; rg < 4; rg++) tsum[rg] += __shfl_xor(tsum[rg], d);
#pragma unroll
        for (int rg = 0; rg < 4; rg++) lrun[rg] = lrun[rg] * corr[rg] + tsum[rg];
#pragma unroll
        for (int j6 = 0; j6 < 6; j6++)
#pragma unroll
            for (int rg = 0; rg < 4; rg++) o[j6][rg] *= corr[rg];

        // O += P V
#pragma unroll
        for (int kk = 0; kk < 4; kk++) {
            bf16x8 ap = *(const bf16x8*)&Pl[wid][l15 * 136 + kk * 32 + l4 * 8];
#pragma unroll
            for (int j6 = 0; j6 < 6; j6++) {
                bf16x8 bv8 = *(const bf16x8*)&Vt[(j6 * 16 + l15) * 136 + kk * 32 + l4 * 8];
                o[j6] = mfma16(ap, bv8, o[j6]);
            }
        }
    }

    float inv[4];
#pragma unroll
    for (int rg = 0; rg < 4; rg++) inv[rg] = 1.f / lrun[rg];
    const size_t orow = (size_t)(qbase + (qblk << 6) + (wid << 4));
#pragma unroll
    for (int j6 = 0; j6 < 6; j6++)
#pragma unroll
        for (int rg = 0; rg < 4; rg++)
            attn[(orow + l4 * 4 + rg) * 768 + h * 96 + j6 * 16 + l15] = f2bf(o[j6][rg] * inv[rg]);
}

// ---------- LN1 + masked-pool accumulation (one chunk) ----------
__global__ __launch_bounds__(256) void k_ln_pool(const float* __restrict__ X,
                                                 const int* __restrict__ vmaskc,
                                                 const int* __restrict__ tmaskc,
                                                 const float* __restrict__ g,
                                                 const float* __restrict__ bb,
                                                 float* __restrict__ pooled,
                                                 int mvisL, int bg0) {
    __shared__ float pool[768];
    const int tid = threadIdx.x, wid = tid >> 6, lane = tid & 63;
    const int row0 = blockIdx.x << 5;
    const bool vis = row0 < mvisL;
    const int* mask = vis ? vmaskc : tmaskc;
    const int mbase = vis ? 0 : mvisL;
    const int bl = vis ? (row0 >> 10) : ((row0 - mvisL) >> 9);
    float* pout = pooled + (vis ? 0 : 12288) + (size_t)(bg0 + bl) * 768;

    float gv[12], bv2[12];
#pragma unroll
    for (int k = 0; k < 12; k++) { gv[k] = g[lane + k * 64]; bv2[k] = bb[lane + k * 64]; }
    float acc[12] = {};
    for (int rr = 0; rr < 8; ++rr) {
        const int row = row0 + (wid << 3) + rr;
        const float* x = X + (size_t)row * 768;
        float xs[12], sm = 0.f, s2 = 0.f;
#pragma unroll
        for (int k = 0; k < 12; k++) {
            float tv = x[lane + k * 64];
            xs[k] = tv; sm += tv; s2 += tv * tv;
        }
#pragma unroll
        for (int d = 1; d < 64; d <<= 1) { sm += __shfl_xor(sm, d); s2 += __shfl_xor(s2, d); }
        const float mean = sm * (1.f / 768.f);
        const float rstd = rsqrtf(s2 * (1.f / 768.f) - mean * mean + 1e-5f);
        const float mv = (float)mask[row - mbase];
#pragma unroll
        for (int k = 0; k < 12; k++) acc[k] += ((xs[k] - mean) * rstd * gv[k] + bv2[k]) * mv;
    }
    pool[tid] = 0.f; pool[tid + 256] = 0.f; pool[tid + 512] = 0.f;
    __syncthreads();
#pragma unroll
    for (int k = 0; k < 12; k++) atomicAdd(&pool[lane + k * 64], acc[k]);
    __syncthreads();
    atomicAdd(&pout[tid], pool[tid]);
    atomicAdd(&pout[tid + 256], pool[tid + 256]);
    atomicAdd(&pout[tid + 512], pool[tid + 512]);
}

// ---------- final: mask counts, pooled concat @ Wf + bf, LN2 ----------
__device__ __forceinline__ float blk_sum(float v, volatile float* tmp) {
#pragma unroll
    for (int d = 1; d < 64; d <<= 1) v += __shfl_xor(v, d);
    __syncthreads();
    if ((threadIdx.x & 63) == 0) tmp[threadIdx.x >> 6] = v;
    __syncthreads();
    return tmp[0] + tmp[1] + tmp[2] + tmp[3];
}

__global__ __launch_bounds__(256) void k_final(const float* __restrict__ pooled,
                                               const int* __restrict__ vmask,
                                               const int* __restrict__ tmask,
                                               const float* __restrict__ Wf,
                                               const float* __restrict__ bfv,
                                               const float* __restrict__ g2,
                                               const float* __restrict__ b2,
                                               float* __restrict__ out) {
    __shared__ float sh[1536];
    __shared__ float red[4];
    const int b = blockIdx.x, tid = threadIdx.x;
    float cv = 0.f, ct = 0.f;
    for (int i = tid; i < 1024; i += 256) cv += (float)vmask[(b << 10) + i];
    for (int i = tid; i < 512; i += 256) ct += (float)tmask[(b << 9) + i];
    cv = blk_sum(cv, red);
    ct = blk_sum(ct, red);
    const float iv = 1.f / cv, itv = 1.f / ct;
#pragma unroll
    for (int k = 0; k < 3; k++) {
        int j = tid + (k << 8);
        sh[j] = pooled[b * 768 + j] * iv;
        sh[768 + j] = pooled[12288 + b * 768 + j] * itv;
    }
    __syncthreads();
    float f0 = bfv[tid], f1 = bfv[tid + 256], f2 = bfv[tid + 512];
    for (int i = 0; i < 1536; i++) {
        const float pv = sh[i];
        const float* w = Wf + (size_t)i * 768;
        f0 += pv * w[tid];
        f1 += pv * w[tid + 256];
        f2 += pv * w[tid + 512];
    }
    float sm = blk_sum(f0 + f1 + f2, red);
    float s2 = blk_sum(f0 * f0 + f1 * f1 + f2 * f2, red);
    const float mean = sm * (1.f / 768.f);
    const float rstd = rsqrtf(s2 * (1.f / 768.f) - mean * mean + 1e-5f);
    out[b * 768 + tid] = (f0 - mean) * rstd * g2[tid] + b2[tid];
    out[b * 768 + tid + 256] = (f1 - mean) * rstd * g2[tid + 256] + b2[tid + 256];
    out[b * 768 + tid + 512] = (f2 - mean) * rstd * g2[tid + 512] + b2[tid + 512];
}

// ---------- host ----------
extern "C" void kernel_launch(void* const* d_in, const int* in_sizes, int n_in,
                              void* d_out, int out_size, void* d_ws, size_t ws_size,
                              hipStream_t stream) {
    (void)in_sizes; (void)n_in; (void)out_size;
    const float* vf = (const float*)d_in[0];
    const float* tf = (const float*)d_in[1];
    const int* vmask = (const int*)d_in[2];
    const int* tmask = (const int*)d_in[3];
    const float* Wq = (const float*)d_in[4];
    const float* bq = (const float*)d_in[5];
    const float* Wk = (const float*)d_in[6];
    const float* bk = (const float*)d_in[7];
    const float* Wv = (const float*)d_in[8];
    const float* bv = (const float*)d_in[9];
    const float* Wo = (const float*)d_in[10];
    const float* bo = (const float*)d_in[11];
    const float* g1 = (const float*)d_in[12];
    const float* b1 = (const float*)d_in[13];
    const float* Wf = (const float*)d_in[14];
    const float* bfv = (const float*)d_in[15];
    const float* g2 = (const float*)d_in[16];
    const float* b2 = (const float*)d_in[17];
    float* outp = (float*)d_out;

    // pick largest chunk (CH batches) fitting ws_size: bytes = 4,826,112 + CH*9,437,184
    int CH = 16;
    while (CH > 1 && 4826112ull + (size_t)CH * 9437184ull > ws_size) CH >>= 1;
    const int NC = 16 / CH;

    // workspace layout
    char* ws = (char*)d_ws;
    u16*   wsW      = (u16*)(ws);                          // QKV weights B^T [2304][768] bf16
    u16*   wsWo     = (u16*)(ws + 3538944);                // Wo B^T [768][768] bf16
    float* wsBqkv   = (float*)(ws + 4718592);              // [2304] f32
    float* wsPooled = (float*)(ws + 4727808);              // [2][16][768] f32
    u16*   wsX      = (u16*)(ws + 4826112);                // [R][768] bf16 (reused as attn out)
    char*  qkvBase  = ws + 4826112 + (size_t)CH * 2359296;
    u16*   wsQKV    = (u16*)qkvBase;                       // [R][2304] bf16 (reused as Oproj f32)
    float* wsOproj  = (float*)qkvBase;
    u16*   wsAttn   = wsX;

    // prep (once)
    k_transpose<<<dim3(144), dim3(256), 0, stream>>>(Wq, wsW, 768, 768);
    k_transpose<<<dim3(144), dim3(256), 0, stream>>>(Wk, wsW + 589824, 768, 768);
    k_transpose<<<dim3(144), dim3(256), 0, stream>>>(Wv, wsW + 1179648, 768, 768);
    k_transpose<<<dim3(144), dim3(256), 0, stream>>>(Wo, wsWo, 768, 768);
    k_bias<<<dim3(9), dim3(256), 0, stream>>>(bq, bk, bv, wsBqkv);
    k_zero<<<dim3(96), dim3(256), 0, stream>>>(wsPooled);

    for (int c = 0; c < NC; ++c) {
        const float* vfc = vf + (size_t)c * CH * 1024 * 768;
        const float* tfc = tf + (size_t)c * CH * 512 * 768;
        const int* vmc = vmask + c * CH * 1024;
        const int* tmc = tmask + c * CH * 512;

        k_cvt_x<<<dim3(CH * 1152), dim3(256), 0, stream>>>(vfc, tfc, wsX, CH * 196608);

        // QKV = X @ Wqkv + b   (M=CH*1536, N=2304, K=768)
        k_gemm<true, false><<<dim3(CH * 216), dim3(256), 0, stream>>>(
            wsX, wsW, wsBqkv, nullptr, nullptr, (void*)wsQKV, 2304, 768, 0);

        // cross attention both directions (writes into wsX region)
        k_attn<<<dim3(CH * 192), dim3(256), 0, stream>>>(wsQKV, vmc, tmc, wsAttn, CH);

        // O-proj + bias + residual  (M=CH*1536, N=768, K=768), f32 out (into QKV region)
        k_gemm<false, true><<<dim3(CH * 72), dim3(256), 0, stream>>>(
            wsAttn, wsWo, bo, vfc, tfc, (void*)wsOproj, 768, 768, CH * 1024);

        k_ln_pool<<<dim3(CH * 48), dim3(256), 0, stream>>>(
            wsOproj, vmc, tmc, g1, b1, wsPooled, CH * 1024, c * CH);
    }

    k_final<<<dim3(16), dim3(256), 0, stream>>>(wsPooled, vmask, tmask, Wf, bfv, g2, b2, outp);
}

// Round 3
// 541.731 us; speedup vs baseline: 1.1256x; 1.1256x over previous
//
#include <hip/hip_runtime.h>

typedef __bf16 bf16x8 __attribute__((ext_vector_type(8)));
typedef float f32x4 __attribute__((ext_vector_type(4)));
typedef unsigned short u16;
typedef unsigned int u32;
typedef u16 u16x8 __attribute__((ext_vector_type(8)));
typedef u16 u16x4 __attribute__((ext_vector_type(4)));

// B=16, SV=1024, ST=512, D=768, H=8, DH=96. Chunked over CH batches,
// R = CH*1536 rows (CH*1024 visual then CH*512 text).

__device__ __forceinline__ u16 f2bf(float f) {
    u32 u = __builtin_bit_cast(u32, f);
    u32 r = u + 0x7FFFu + ((u >> 16) & 1u);
    return (u16)(r >> 16);
}

__device__ __forceinline__ f32x4 mfma16(bf16x8 a, bf16x8 b, f32x4 c) {
    return __builtin_amdgcn_mfma_f32_16x16x32_bf16(a, b, c, 0, 0, 0);
}

#define GLOAD_LDS16(g, l) __builtin_amdgcn_global_load_lds( \
    (__attribute__((address_space(1))) void*)(g), \
    (__attribute__((address_space(3))) void*)(l), 16, 0, 0)

// ---------- prep kernels ----------

__global__ __launch_bounds__(256) void k_cvt_x(const float* __restrict__ vf,
                                               const float* __restrict__ tf,
                                               u16* __restrict__ X, int nvis4) {
    int i = blockIdx.x * 256 + threadIdx.x;
    f32x4 v = (i < nvis4) ? ((const f32x4*)vf)[i] : ((const f32x4*)tf)[i - nvis4];
    u16x4 o = { f2bf(v[0]), f2bf(v[1]), f2bf(v[2]), f2bf(v[3]) };
    ((u16x4*)X)[i] = o;
}

// src f32 [K0][N0] -> dst bf16 [N0][K0]   (64x64 LDS tiles)
__global__ __launch_bounds__(256) void k_transpose(const float* __restrict__ src,
                                                   u16* __restrict__ dst,
                                                   int K0, int N0) {
    __shared__ float t[64][65];
    int ntx = N0 >> 6;
    int k0 = (blockIdx.x / ntx) << 6, n0 = (blockIdx.x % ntx) << 6;
    int c = threadIdx.x & 63, rr = threadIdx.x >> 6;
#pragma unroll
    for (int q = 0; q < 16; q++) {
        int r = q * 4 + rr;
        t[r][c] = src[(size_t)(k0 + r) * N0 + n0 + c];
    }
    __syncthreads();
#pragma unroll
    for (int q = 0; q < 16; q++) {
        int r = q * 4 + rr;
        dst[(size_t)(n0 + r) * K0 + k0 + c] = f2bf(t[c][r]);
    }
}

__global__ __launch_bounds__(256) void k_bias(const float* __restrict__ bq,
                                              const float* __restrict__ bk,
                                              const float* __restrict__ bv,
                                              float* __restrict__ bqkv) {
    int n = blockIdx.x * 256 + threadIdx.x;
    if (n < 2304) {
        const float* s = (n < 768) ? bq : ((n < 1536) ? bk : bv);
        int r = (n < 768) ? n : ((n < 1536) ? n - 768 : n - 1536);
        bqkv[n] = s[r];
    }
}

__global__ __launch_bounds__(256) void k_zero(float* __restrict__ p) {
    p[blockIdx.x * 256 + threadIdx.x] = 0.f;
}

// ---------- V global transpose: QKV V-cols [R][768] -> VtG [768][R] bf16 ----------
__global__ __launch_bounds__(256) void k_vtrans(const u16* __restrict__ qkv,
                                                u16* __restrict__ VtG, int Rtot) {
    __shared__ alignas(16) u16 t[64][72];   // stride 72 u16 = 144B (16B-aligned rows)
    const int kt = blockIdx.x / 12, dt = blockIdx.x % 12;
    const int k0 = kt << 6, d0 = dt << 6;
    const int tid = threadIdx.x;
#pragma unroll
    for (int it = 0; it < 2; it++) {        // stage 64x64: r=c/8, cc=c%8 (coalesced)
        int c = it * 256 + tid;
        int r = c >> 3, cc = c & 7;
        u16x8 v = *(const u16x8*)&qkv[(size_t)(k0 + r) * 2304 + 1536 + d0 + cc * 8];
        *(u16x8*)&t[r][cc * 8] = v;
    }
    __syncthreads();
#pragma unroll
    for (int it = 0; it < 2; it++) {        // out: k8=c&7 (fast, coalesced 64B), d=(c>>3)
        int c = it * 256 + tid;
        int k8 = c & 7, d = c >> 3;
        u16x8 o;
#pragma unroll
        for (int e = 0; e < 8; e++) o[e] = t[k8 * 8 + e][d];
        *(u16x8*)&VtG[(size_t)(d0 + d) * Rtot + k0 + k8 * 8] = o;
    }
}

// ---------- GEMM: C[R][N] = A[R][K] * Bt[N][K]^T + bias (+residual) ----------
template <bool OUT_BF16, bool ADD_RES>
__global__ __launch_bounds__(256) void k_gemm(const u16* __restrict__ A,
                                              const u16* __restrict__ Bt,
                                              const float* __restrict__ bias,
                                              const float* __restrict__ resA,
                                              const float* __restrict__ resB,
                                              void* __restrict__ Cout,
                                              int Ndim, int Kdim, int mvisL) {
    __shared__ alignas(16) u16 sA[128 * 32];
    __shared__ alignas(16) u16 sB[128 * 32];
    const int tid = threadIdx.x, wid = tid >> 6, lane = tid & 63;
    const int ntiles = Ndim >> 7;
    const int mt = blockIdx.x / ntiles, nt = blockIdx.x - mt * ntiles;
    const int m0 = mt << 7, n0 = nt << 7;
    const int wm = wid >> 1, wn = wid & 1;
    f32x4 acc[4][4] = {};

    const int r0 = tid >> 2, p0 = tid & 3;
    const int r1 = 64 + (tid >> 2);
    const u16* ga0 = A + (size_t)(m0 + r0) * Kdim + p0 * 8;
    const u16* ga1 = A + (size_t)(m0 + r1) * Kdim + p0 * 8;
    const u16* gb0 = Bt + (size_t)(n0 + r0) * Kdim + p0 * 8;
    const u16* gb1 = Bt + (size_t)(n0 + r1) * Kdim + p0 * 8;
    u16* lA0 = sA + (wid * 64) * 8;
    u16* lA1 = sA + (256 + wid * 64) * 8;
    u16* lB0 = sB + (wid * 64) * 8;
    u16* lB1 = sB + (256 + wid * 64) * 8;

    const int arow = (wm << 6) + (lane & 15);
    const int brow = (wn << 6) + (lane & 15);
    const int kg = (lane >> 4) * 8;

    for (int kt = 0; kt < Kdim; kt += 32) {
        GLOAD_LDS16(ga0 + kt, lA0);
        GLOAD_LDS16(ga1 + kt, lA1);
        GLOAD_LDS16(gb0 + kt, lB0);
        GLOAD_LDS16(gb1 + kt, lB1);
        __syncthreads();
        bf16x8 av[4], bw[4];
#pragma unroll
        for (int i = 0; i < 4; i++) av[i] = *(const bf16x8*)&sA[(arow + i * 16) * 32 + kg];
#pragma unroll
        for (int j = 0; j < 4; j++) bw[j] = *(const bf16x8*)&sB[(brow + j * 16) * 32 + kg];
#pragma unroll
        for (int i = 0; i < 4; i++)
#pragma unroll
            for (int j = 0; j < 4; j++) acc[i][j] = mfma16(av[i], bw[j], acc[i][j]);
        __syncthreads();
    }

    const int col0 = n0 + (wn << 6) + (lane & 15);
    const int rowb = m0 + (wm << 6) + ((lane >> 4) << 2);
    float bvals[4];
#pragma unroll
    for (int j = 0; j < 4; j++) bvals[j] = bias[col0 + j * 16];
#pragma unroll
    for (int i = 0; i < 4; i++) {
#pragma unroll
        for (int rg = 0; rg < 4; rg++) {
            const int row = rowb + i * 16 + rg;
            const float* rp = nullptr;
            if constexpr (ADD_RES)
                rp = (row < mvisL) ? resA + (size_t)row * 768
                                   : resB + (size_t)(row - mvisL) * 768;
#pragma unroll
            for (int j = 0; j < 4; j++) {
                const int col = col0 + j * 16;
                float v = acc[i][j][rg] + bvals[j];
                if constexpr (ADD_RES) v += rp[col];
                if constexpr (OUT_BF16)
                    ((u16*)Cout)[(size_t)row * Ndim + col] = f2bf(v);
                else
                    ((float*)Cout)[(size_t)row * Ndim + col] = v;
            }
        }
    }
}

// ---------- fused cross-attention ----------
// K staged [128][16 slots] swizzled (slot s holds k8 = s^(r&7)); V from VtG,
// staged [96][16 slots] swizzled; both via global_load_lds (linear dest,
// inverse-swizzled global source, swizzled read). Pl [16][128] swizzled.
__global__ __launch_bounds__(256) void k_attn(const u16* __restrict__ qkv,
                                              const u16* __restrict__ VtG,
                                              const int* __restrict__ vmaskc,
                                              const int* __restrict__ tmaskc,
                                              u16* __restrict__ attn, int CHn, int Rtot) {
    __shared__ alignas(16) u16 Kl[128 * 128];
    __shared__ alignas(16) u16 Vt[96 * 128];
    __shared__ alignas(16) u16 Pl[4][16 * 128];
    __shared__ float mk[128];

    int bx = blockIdx.x;
    int b, h, qblk, Sk, qbase, kbase;
    const int* mask;
    const int vcap = CHn << 7;
    if (bx < vcap) {  // visual queries attend to text
        qblk = bx & 15; h = (bx >> 4) & 7; b = bx >> 7;
        qbase = b << 10; kbase = (CHn << 10) + (b << 9); Sk = 512; mask = tmaskc + (b << 9);
    } else {          // text queries attend to visual
        int bx2 = bx - vcap;
        qblk = bx2 & 7; h = (bx2 >> 3) & 7; b = bx2 >> 6;
        qbase = (CHn << 10) + (b << 9); kbase = b << 10; Sk = 1024; mask = vmaskc + (b << 10);
    }
    const int tid = threadIdx.x, wid = tid >> 6, lane = tid & 63;
    const int l15 = lane & 15, l4 = lane >> 4;

    const int qr = qbase + (qblk << 6) + (wid << 4) + l15;
    bf16x8 aq[3];
#pragma unroll
    for (int kk = 0; kk < 3; kk++)
        aq[kk] = *(const bf16x8*)&qkv[(size_t)qr * 2304 + h * 96 + kk * 32 + l4 * 8];

    f32x4 o[6] = {};
    float mrun[4] = {-1e30f, -1e30f, -1e30f, -1e30f};
    float lrun[4] = {0.f, 0.f, 0.f, 0.f};
    const float scale = 0.10206207261596577f;  // 1/sqrt(96)
    const int ntile = Sk >> 7;

    for (int t = 0; t < ntile; ++t) {
        __syncthreads();
        // stage K tile: 2048 chunks of 16B, linear LDS, source inverse-swizzled
#pragma unroll
        for (int it = 0; it < 8; ++it) {
            const int cb = it * 256 + (wid << 6);
            const int c = cb + lane;
            const int r = c >> 4, s8 = c & 15;
            const int k8 = s8 ^ (r & 7);
            const u16* src = qkv + (size_t)(kbase + (t << 7) + r) * 2304 + 768 + h * 96
                             + (k8 < 12 ? k8 * 8 : 0);
            GLOAD_LDS16(src, Kl + (size_t)cb * 8);
        }
        // stage V tile from VtG: 1536 chunks
#pragma unroll
        for (int it = 0; it < 6; ++it) {
            const int cb = it * 256 + (wid << 6);
            const int c = cb + lane;
            const int d = c >> 4, s8 = c & 15;
            const int k8 = s8 ^ (d & 7);
            const u16* src = VtG + (size_t)(h * 96 + d) * Rtot + kbase + (t << 7) + k8 * 8;
            GLOAD_LDS16(src, Vt + (size_t)cb * 8);
        }
        if (tid < 128) mk[tid] = (float)mask[(t << 7) + tid];
        __syncthreads();

        // S = Q K^T
        f32x4 s[8];
#pragma unroll
        for (int j = 0; j < 8; j++) {
            f32x4 cj = {0.f, 0.f, 0.f, 0.f};
#pragma unroll
            for (int kk = 0; kk < 3; kk++) {
                const int r = j * 16 + l15;
                bf16x8 bk8 = *(const bf16x8*)&Kl[r * 128 + (((kk * 4 + l4) ^ (l15 & 7)) << 3)];
                cj = mfma16(aq[kk], bk8, cj);
            }
            s[j] = cj;
        }
        float tmax[4] = {-1e30f, -1e30f, -1e30f, -1e30f};
#pragma unroll
        for (int j = 0; j < 8; j++) {
            float msk = mk[j * 16 + l15];
#pragma unroll
            for (int rg = 0; rg < 4; rg++) {
                float v = s[j][rg] * scale;
                v = (msk != 0.f) ? v : -1e30f;
                s[j][rg] = v;
                tmax[rg] = fmaxf(tmax[rg], v);
            }
        }
#pragma unroll
        for (int d = 1; d < 16; d <<= 1)
#pragma unroll
            for (int rg = 0; rg < 4; rg++) tmax[rg] = fmaxf(tmax[rg], __shfl_xor(tmax[rg], d));
        float corr[4], tsum[4];
#pragma unroll
        for (int rg = 0; rg < 4; rg++) {
            float mn = fmaxf(mrun[rg], tmax[rg]);
            corr[rg] = __expf(mrun[rg] - mn);
            mrun[rg] = mn;
            tsum[rg] = 0.f;
        }
#pragma unroll
        for (int j = 0; j < 8; j++)
#pragma unroll
            for (int rg = 0; rg < 4; rg++) {
                float p = __expf(s[j][rg] - mrun[rg]);
                tsum[rg] += p;
                const int prow = l4 * 4 + rg;
                Pl[wid][prow * 128 + ((j * 16 + l15) ^ ((prow & 7) << 3))] = f2bf(p);
            }
#pragma unroll
        for (int d = 1; d < 16; d <<= 1)
#pragma unroll
            for (int rg = 0; rg < 4; rg++) tsum[rg] += __shfl_xor(tsum[rg], d);
#pragma unroll
        for (int rg = 0; rg < 4; rg++) lrun[rg] = lrun[rg] * corr[rg] + tsum[rg];
#pragma unroll
        for (int j6 = 0; j6 < 6; j6++)
#pragma unroll
            for (int rg = 0; rg < 4; rg++) o[j6][rg] *= corr[rg];

        // O += P V
#pragma unroll
        for (int kk = 0; kk < 4; kk++) {
            bf16x8 ap = *(const bf16x8*)&Pl[wid][l15 * 128 + (((kk * 4 + l4) ^ (l15 & 7)) << 3)];
#pragma unroll
            for (int j6 = 0; j6 < 6; j6++) {
                const int d = j6 * 16 + l15;
                bf16x8 bv8 = *(const bf16x8*)&Vt[d * 128 + (((kk * 4 + l4) ^ (l15 & 7)) << 3)];
                o[j6] = mfma16(ap, bv8, o[j6]);
            }
        }
    }

    float inv[4];
#pragma unroll
    for (int rg = 0; rg < 4; rg++) inv[rg] = 1.f / lrun[rg];
    const size_t orow = (size_t)(qbase + (qblk << 6) + (wid << 4));
#pragma unroll
    for (int j6 = 0; j6 < 6; j6++)
#pragma unroll
        for (int rg = 0; rg < 4; rg++)
            attn[(orow + l4 * 4 + rg) * 768 + h * 96 + j6 * 16 + l15] = f2bf(o[j6][rg] * inv[rg]);
}

// ---------- LN1 + masked-pool accumulation ----------
__global__ __launch_bounds__(256) void k_ln_pool(const float* __restrict__ X,
                                                 const int* __restrict__ vmaskc,
                                                 const int* __restrict__ tmaskc,
                                                 const float* __restrict__ g,
                                                 const float* __restrict__ bb,
                                                 float* __restrict__ pooled,
                                                 int mvisL, int bg0) {
    __shared__ float pool[768];
    const int tid = threadIdx.x, wid = tid >> 6, lane = tid & 63;
    const int row0 = blockIdx.x << 5;
    const bool vis = row0 < mvisL;
    const int* mask = vis ? vmaskc : tmaskc;
    const int mbase = vis ? 0 : mvisL;
    const int bl = vis ? (row0 >> 10) : ((row0 - mvisL) >> 9);
    float* pout = pooled + (vis ? 0 : 12288) + (size_t)(bg0 + bl) * 768;

    float gv[12], bv2[12];
#pragma unroll
    for (int k = 0; k < 12; k++) { gv[k] = g[lane + k * 64]; bv2[k] = bb[lane + k * 64]; }
    float acc[12] = {};
    for (int rr = 0; rr < 8; ++rr) {
        const int row = row0 + (wid << 3) + rr;
        const float* x = X + (size_t)row * 768;
        float xs[12], sm = 0.f, s2 = 0.f;
#pragma unroll
        for (int k = 0; k < 12; k++) {
            float tv = x[lane + k * 64];
            xs[k] = tv; sm += tv; s2 += tv * tv;
        }
#pragma unroll
        for (int d = 1; d < 64; d <<= 1) { sm += __shfl_xor(sm, d); s2 += __shfl_xor(s2, d); }
        const float mean = sm * (1.f / 768.f);
        const float rstd = rsqrtf(s2 * (1.f / 768.f) - mean * mean + 1e-5f);
        const float mv = (float)mask[row - mbase];
#pragma unroll
        for (int k = 0; k < 12; k++) acc[k] += ((xs[k] - mean) * rstd * gv[k] + bv2[k]) * mv;
    }
    pool[tid] = 0.f; pool[tid + 256] = 0.f; pool[tid + 512] = 0.f;
    __syncthreads();
#pragma unroll
    for (int k = 0; k < 12; k++) atomicAdd(&pool[lane + k * 64], acc[k]);
    __syncthreads();
    atomicAdd(&pout[tid], pool[tid]);
    atomicAdd(&pout[tid + 256], pool[tid + 256]);
    atomicAdd(&pout[tid + 512], pool[tid + 512]);
}

// ---------- final ----------
__device__ __forceinline__ float blk_sum(float v, volatile float* tmp) {
#pragma unroll
    for (int d = 1; d < 64; d <<= 1) v += __shfl_xor(v, d);
    __syncthreads();
    if ((threadIdx.x & 63) == 0) tmp[threadIdx.x >> 6] = v;
    __syncthreads();
    return tmp[0] + tmp[1] + tmp[2] + tmp[3];
}

__global__ __launch_bounds__(256) void k_final(const float* __restrict__ pooled,
                                               const int* __restrict__ vmask,
                                               const int* __restrict__ tmask,
                                               const float* __restrict__ Wf,
                                               const float* __restrict__ bfv,
                                               const float* __restrict__ g2,
                                               const float* __restrict__ b2,
                                               float* __restrict__ out) {
    __shared__ float sh[1536];
    __shared__ float red[4];
    const int b = blockIdx.x, tid = threadIdx.x;
    float cv = 0.f, ct = 0.f;
    for (int i = tid; i < 1024; i += 256) cv += (float)vmask[(b << 10) + i];
    for (int i = tid; i < 512; i += 256) ct += (float)tmask[(b << 9) + i];
    cv = blk_sum(cv, red);
    ct = blk_sum(ct, red);
    const float iv = 1.f / cv, itv = 1.f / ct;
#pragma unroll
    for (int k = 0; k < 3; k++) {
        int j = tid + (k << 8);
        sh[j] = pooled[b * 768 + j] * iv;
        sh[768 + j] = pooled[12288 + b * 768 + j] * itv;
    }
    __syncthreads();
    float f0 = bfv[tid], f1 = bfv[tid + 256], f2 = bfv[tid + 512];
    for (int i = 0; i < 1536; i++) {
        const float pv = sh[i];
        const float* w = Wf + (size_t)i * 768;
        f0 += pv * w[tid];
        f1 += pv * w[tid + 256];
        f2 += pv * w[tid + 512];
    }
    float sm = blk_sum(f0 + f1 + f2, red);
    float s2 = blk_sum(f0 * f0 + f1 * f1 + f2 * f2, red);
    const float mean = sm * (1.f / 768.f);
    const float rstd = rsqrtf(s2 * (1.f / 768.f) - mean * mean + 1e-5f);
    out[b * 768 + tid] = (f0 - mean) * rstd * g2[tid] + b2[tid];
    out[b * 768 + tid + 256] = (f1 - mean) * rstd * g2[tid + 256] + b2[tid + 256];
    out[b * 768 + tid + 512] = (f2 - mean) * rstd * g2[tid + 512] + b2[tid + 512];
}

// ---------- host ----------
extern "C" void kernel_launch(void* const* d_in, const int* in_sizes, int n_in,
                              void* d_out, int out_size, void* d_ws, size_t ws_size,
                              hipStream_t stream) {
    (void)in_sizes; (void)n_in; (void)out_size;
    const float* vf = (const float*)d_in[0];
    const float* tf = (const float*)d_in[1];
    const int* vmask = (const int*)d_in[2];
    const int* tmask = (const int*)d_in[3];
    const float* Wq = (const float*)d_in[4];
    const float* bq = (const float*)d_in[5];
    const float* Wk = (const float*)d_in[6];
    const float* bk = (const float*)d_in[7];
    const float* Wv = (const float*)d_in[8];
    const float* bv = (const float*)d_in[9];
    const float* Wo = (const float*)d_in[10];
    const float* bo = (const float*)d_in[11];
    const float* g1 = (const float*)d_in[12];
    const float* b1 = (const float*)d_in[13];
    const float* Wf = (const float*)d_in[14];
    const float* bfv = (const float*)d_in[15];
    const float* g2 = (const float*)d_in[16];
    const float* b2 = (const float*)d_in[17];
    float* outp = (float*)d_out;

    // footprint = 4,826,112 + CH * (2,359,296 X + 7,077,888 QKV + 2,359,296 VtG)
    int CH = 16;
    while (CH > 1 && 4826112ull + (size_t)CH * 11796480ull > ws_size) CH >>= 1;
    const int NC = 16 / CH;
    const int Rtot = CH * 1536;

    char* ws = (char*)d_ws;
    u16*   wsW      = (u16*)(ws);
    u16*   wsWo     = (u16*)(ws + 3538944);
    float* wsBqkv   = (float*)(ws + 4718592);
    float* wsPooled = (float*)(ws + 4727808);
    u16*   wsX      = (u16*)(ws + 4826112);                 // [R][768] bf16 (reused: attn out)
    char*  qkvBase  = ws + 4826112 + (size_t)CH * 2359296;
    u16*   wsQKV    = (u16*)qkvBase;                         // [R][2304] bf16 (reused: Oproj f32)
    float* wsOproj  = (float*)qkvBase;
    u16*   wsVtG    = (u16*)(qkvBase + (size_t)CH * 7077888);// [768][R] bf16
    u16*   wsAttn   = wsX;

    k_transpose<<<dim3(144), dim3(256), 0, stream>>>(Wq, wsW, 768, 768);
    k_transpose<<<dim3(144), dim3(256), 0, stream>>>(Wk, wsW + 589824, 768, 768);
    k_transpose<<<dim3(144), dim3(256), 0, stream>>>(Wv, wsW + 1179648, 768, 768);
    k_transpose<<<dim3(144), dim3(256), 0, stream>>>(Wo, wsWo, 768, 768);
    k_bias<<<dim3(9), dim3(256), 0, stream>>>(bq, bk, bv, wsBqkv);
    k_zero<<<dim3(96), dim3(256), 0, stream>>>(wsPooled);

    for (int c = 0; c < NC; ++c) {
        const float* vfc = vf + (size_t)c * CH * 1024 * 768;
        const float* tfc = tf + (size_t)c * CH * 512 * 768;
        const int* vmc = vmask + c * CH * 1024;
        const int* tmc = tmask + c * CH * 512;

        k_cvt_x<<<dim3(CH * 1152), dim3(256), 0, stream>>>(vfc, tfc, wsX, CH * 196608);

        k_gemm<true, false><<<dim3(CH * 216), dim3(256), 0, stream>>>(
            wsX, wsW, wsBqkv, nullptr, nullptr, (void*)wsQKV, 2304, 768, 0);

        k_vtrans<<<dim3(CH * 288), dim3(256), 0, stream>>>(wsQKV, wsVtG, Rtot);

        k_attn<<<dim3(CH * 192), dim3(256), 0, stream>>>(
            wsQKV, wsVtG, vmc, tmc, wsAttn, CH, Rtot);

        k_gemm<false, true><<<dim3(CH * 72), dim3(256), 0, stream>>>(
            wsAttn, wsWo, bo, vfc, tfc, (void*)wsOproj, 768, 768, CH * 1024);

        k_ln_pool<<<dim3(CH * 48), dim3(256), 0, stream>>>(
            wsOproj, vmc, tmc, g1, b1, wsPooled, CH * 1024, c * CH);
    }

    k_final<<<dim3(16), dim3(256), 0, stream>>>(wsPooled, vmask, tmask, Wf, bfv, g2, b2, outp);
}

// Round 4
// 539.938 us; speedup vs baseline: 1.1294x; 1.0033x over previous
//
#include <hip/hip_runtime.h>

typedef __bf16 bf16x8 __attribute__((ext_vector_type(8)));
typedef float f32x4 __attribute__((ext_vector_type(4)));
typedef unsigned short u16;
typedef unsigned int u32;
typedef u16 u16x8 __attribute__((ext_vector_type(8)));
typedef u16 u16x4 __attribute__((ext_vector_type(4)));

// B=16, SV=1024, ST=512, D=768, H=8, DH=96. Chunked over CH batches,
// R = CH*1536 rows (CH*1024 visual then CH*512 text).

__device__ __forceinline__ u16 f2bf(float f) {
    u32 u = __builtin_bit_cast(u32, f);
    u32 r = u + 0x7FFFu + ((u >> 16) & 1u);
    return (u16)(r >> 16);
}

__device__ __forceinline__ f32x4 mfma16(bf16x8 a, bf16x8 b, f32x4 c) {
    return __builtin_amdgcn_mfma_f32_16x16x32_bf16(a, b, c, 0, 0, 0);
}

#define GLOAD_LDS16(g, l) __builtin_amdgcn_global_load_lds( \
    (__attribute__((address_space(1))) void*)(g), \
    (__attribute__((address_space(3))) void*)(l), 16, 0, 0)

// ---------- prep kernels ----------

__global__ __launch_bounds__(256) void k_cvt_x(const float* __restrict__ vf,
                                               const float* __restrict__ tf,
                                               u16* __restrict__ X, int nvis4) {
    int i = blockIdx.x * 256 + threadIdx.x;
    f32x4 v = (i < nvis4) ? ((const f32x4*)vf)[i] : ((const f32x4*)tf)[i - nvis4];
    u16x4 o = { f2bf(v[0]), f2bf(v[1]), f2bf(v[2]), f2bf(v[3]) };
    ((u16x4*)X)[i] = o;
}

// src f32 [K0][N0] -> dst bf16 [N0][K0]   (64x64 LDS tiles)
__global__ __launch_bounds__(256) void k_transpose(const float* __restrict__ src,
                                                   u16* __restrict__ dst,
                                                   int K0, int N0) {
    __shared__ float t[64][65];
    int ntx = N0 >> 6;
    int k0 = (blockIdx.x / ntx) << 6, n0 = (blockIdx.x % ntx) << 6;
    int c = threadIdx.x & 63, rr = threadIdx.x >> 6;
#pragma unroll
    for (int q = 0; q < 16; q++) {
        int r = q * 4 + rr;
        t[r][c] = src[(size_t)(k0 + r) * N0 + n0 + c];
    }
    __syncthreads();
#pragma unroll
    for (int q = 0; q < 16; q++) {
        int r = q * 4 + rr;
        dst[(size_t)(n0 + r) * K0 + k0 + c] = f2bf(t[c][r]);
    }
}

__global__ __launch_bounds__(256) void k_bias(const float* __restrict__ bq,
                                              const float* __restrict__ bk,
                                              const float* __restrict__ bv,
                                              float* __restrict__ bqkv) {
    int n = blockIdx.x * 256 + threadIdx.x;
    if (n < 2304) {
        const float* s = (n < 768) ? bq : ((n < 1536) ? bk : bv);
        int r = (n < 768) ? n : ((n < 1536) ? n - 768 : n - 1536);
        bqkv[n] = s[r];
    }
}

__global__ __launch_bounds__(256) void k_zero(float* __restrict__ p) {
    p[blockIdx.x * 256 + threadIdx.x] = 0.f;
}

// ---------- V global transpose: QKV V-cols [R][768] -> VtG [768][R] bf16 ----------
__global__ __launch_bounds__(256) void k_vtrans(const u16* __restrict__ qkv,
                                                u16* __restrict__ VtG, int Rtot) {
    __shared__ alignas(16) u16 t[64][72];
    const int kt = blockIdx.x / 12, dt = blockIdx.x % 12;
    const int k0 = kt << 6, d0 = dt << 6;
    const int tid = threadIdx.x;
#pragma unroll
    for (int it = 0; it < 2; it++) {
        int c = it * 256 + tid;
        int r = c >> 3, cc = c & 7;
        u16x8 v = *(const u16x8*)&qkv[(size_t)(k0 + r) * 2304 + 1536 + d0 + cc * 8];
        *(u16x8*)&t[r][cc * 8] = v;
    }
    __syncthreads();
#pragma unroll
    for (int it = 0; it < 2; it++) {
        int c = it * 256 + tid;
        int k8 = c & 7, d = c >> 3;
        u16x8 o;
#pragma unroll
        for (int e = 0; e < 8; e++) o[e] = t[k8 * 8 + e][d];
        *(u16x8*)&VtG[(size_t)(d0 + d) * Rtot + k0 + k8 * 8] = o;
    }
}

// ---------- GEMM: C[R][N] = A[R][K] * Bt[N][K]^T + bias (+residual) ----------
template <bool OUT_BF16, bool ADD_RES>
__global__ __launch_bounds__(256) void k_gemm(const u16* __restrict__ A,
                                              const u16* __restrict__ Bt,
                                              const float* __restrict__ bias,
                                              const float* __restrict__ resA,
                                              const float* __restrict__ resB,
                                              void* __restrict__ Cout,
                                              int Ndim, int Kdim, int mvisL) {
    __shared__ alignas(16) u16 sA[128 * 32];
    __shared__ alignas(16) u16 sB[128 * 32];
    const int tid = threadIdx.x, wid = tid >> 6, lane = tid & 63;
    const int ntiles = Ndim >> 7;
    const int mt = blockIdx.x / ntiles, nt = blockIdx.x - mt * ntiles;
    const int m0 = mt << 7, n0 = nt << 7;
    const int wm = wid >> 1, wn = wid & 1;
    f32x4 acc[4][4] = {};

    const int r0 = tid >> 2, p0 = tid & 3;
    const int r1 = 64 + (tid >> 2);
    const u16* ga0 = A + (size_t)(m0 + r0) * Kdim + p0 * 8;
    const u16* ga1 = A + (size_t)(m0 + r1) * Kdim + p0 * 8;
    const u16* gb0 = Bt + (size_t)(n0 + r0) * Kdim + p0 * 8;
    const u16* gb1 = Bt + (size_t)(n0 + r1) * Kdim + p0 * 8;
    u16* lA0 = sA + (wid * 64) * 8;
    u16* lA1 = sA + (256 + wid * 64) * 8;
    u16* lB0 = sB + (wid * 64) * 8;
    u16* lB1 = sB + (256 + wid * 64) * 8;

    const int arow = (wm << 6) + (lane & 15);
    const int brow = (wn << 6) + (lane & 15);
    const int kg = (lane >> 4) * 8;

    for (int kt = 0; kt < Kdim; kt += 32) {
        GLOAD_LDS16(ga0 + kt, lA0);
        GLOAD_LDS16(ga1 + kt, lA1);
        GLOAD_LDS16(gb0 + kt, lB0);
        GLOAD_LDS16(gb1 + kt, lB1);
        __syncthreads();
        bf16x8 av[4], bw[4];
#pragma unroll
        for (int i = 0; i < 4; i++) av[i] = *(const bf16x8*)&sA[(arow + i * 16) * 32 + kg];
#pragma unroll
        for (int j = 0; j < 4; j++) bw[j] = *(const bf16x8*)&sB[(brow + j * 16) * 32 + kg];
#pragma unroll
        for (int i = 0; i < 4; i++)
#pragma unroll
            for (int j = 0; j < 4; j++) acc[i][j] = mfma16(av[i], bw[j], acc[i][j]);
        __syncthreads();
    }

    const int col0 = n0 + (wn << 6) + (lane & 15);
    const int rowb = m0 + (wm << 6) + ((lane >> 4) << 2);
    float bvals[4];
#pragma unroll
    for (int j = 0; j < 4; j++) bvals[j] = bias[col0 + j * 16];
#pragma unroll
    for (int i = 0; i < 4; i++) {
#pragma unroll
        for (int rg = 0; rg < 4; rg++) {
            const int row = rowb + i * 16 + rg;
            const float* rp = nullptr;
            if constexpr (ADD_RES)
                rp = (row < mvisL) ? resA + (size_t)row * 768
                                   : resB + (size_t)(row - mvisL) * 768;
#pragma unroll
            for (int j = 0; j < 4; j++) {
                const int col = col0 + j * 16;
                float v = acc[i][j][rg] + bvals[j];
                if constexpr (ADD_RES) v += rp[col];
                if constexpr (OUT_BF16)
                    ((u16*)Cout)[(size_t)row * Ndim + col] = f2bf(v);
                else
                    ((float*)Cout)[(size_t)row * Ndim + col] = v;
            }
        }
    }
}

// ---------- fused cross-attention ----------
// QBLK=128 q-rows/block, 8 waves. K [128][16 slots] XOR-swizzled via
// global_load_lds (linear dest, inverse-swizzled source); V likewise from VtG.
// 3-phase: stage-K | {issue-V, QK^T, softmax} | PV  (V latency hides under softmax).
__global__ __launch_bounds__(512) void k_attn(const u16* __restrict__ qkv,
                                              const u16* __restrict__ VtG,
                                              const int* __restrict__ vmaskc,
                                              const int* __restrict__ tmaskc,
                                              u16* __restrict__ attn, int CHn, int Rtot) {
    __shared__ alignas(16) u16 Kl[128 * 128];    // 32 KB
    __shared__ alignas(16) u16 Vt[96 * 128];     // 24 KB
    __shared__ alignas(16) u16 Pl[8][16 * 128];  // 32 KB
    __shared__ float mk[128];

    int bx = blockIdx.x;
    int b, h, qblk, Sk, qbase, kbase;
    const int* mask;
    const int vcap = CHn * 64;
    if (bx < vcap) {  // visual queries attend to text (128-row q-tiles, 8 per b,h)
        qblk = bx & 7; h = (bx >> 3) & 7; b = bx >> 6;
        qbase = b << 10; kbase = (CHn << 10) + (b << 9); Sk = 512; mask = tmaskc + (b << 9);
    } else {          // text queries attend to visual (4 q-tiles per b,h)
        int bx2 = bx - vcap;
        qblk = bx2 & 3; h = (bx2 >> 2) & 7; b = bx2 >> 5;
        qbase = (CHn << 10) + (b << 9); kbase = b << 10; Sk = 1024; mask = vmaskc + (b << 10);
    }
    const int tid = threadIdx.x, wid = tid >> 6, lane = tid & 63;
    const int l15 = lane & 15, l4 = lane >> 4;

    const float scale = 0.10206207261596577f;  // 1/sqrt(96)
    const int qr = qbase + (qblk << 7) + (wid << 4) + l15;
    bf16x8 aq[3];
#pragma unroll
    for (int kk = 0; kk < 3; kk++) {
        bf16x8 tq = *(const bf16x8*)&qkv[(size_t)qr * 2304 + h * 96 + kk * 32 + l4 * 8];
#pragma unroll
        for (int e = 0; e < 8; e++) tq[e] = (__bf16)((float)tq[e] * scale);
        aq[kk] = tq;
    }

    f32x4 o[6] = {};
    float mrun[4] = {-1e30f, -1e30f, -1e30f, -1e30f};
    float lrun[4] = {0.f, 0.f, 0.f, 0.f};
    const int ntile = Sk >> 7;

    for (int t = 0; t < ntile; ++t) {
        __syncthreads();   // prev tile's compute (incl. PV reads of Vt/Kl) done
        // ---- stage K tile: 2048 16B chunks, 4 per thread ----
#pragma unroll
        for (int it = 0; it < 4; ++it) {
            const int cb = it * 512 + (wid << 6);
            const int c = cb + lane;
            const int r = c >> 4, s8 = c & 15;
            const int k8 = s8 ^ (r & 7);
            const u16* src = qkv + (size_t)(kbase + (t << 7) + r) * 2304 + 768 + h * 96
                             + (k8 < 12 ? k8 * 8 : 0);
            GLOAD_LDS16(src, Kl + (size_t)cb * 8);
        }
        if (tid < 128) mk[tid] = mask[(t << 7) + tid] ? 0.f : -1e30f;
        __syncthreads();   // K + mk ready
        // ---- issue V stage (completes at next barrier, hides under softmax) ----
#pragma unroll
        for (int it = 0; it < 3; ++it) {
            const int cb = it * 512 + (wid << 6);
            const int c = cb + lane;
            const int d = c >> 4, s8 = c & 15;
            const int k8 = s8 ^ (d & 7);
            const u16* src = VtG + (size_t)(h * 96 + d) * Rtot + kbase + (t << 7) + k8 * 8;
            GLOAD_LDS16(src, Vt + (size_t)cb * 8);
        }

        // ---- S = Q K^T ----
        f32x4 s[8];
#pragma unroll
        for (int j = 0; j < 8; j++) {
            f32x4 cj = {0.f, 0.f, 0.f, 0.f};
#pragma unroll
            for (int kk = 0; kk < 3; kk++) {
                const int r = j * 16 + l15;
                bf16x8 bk8 = *(const bf16x8*)&Kl[r * 128 + (((kk * 4 + l4) ^ (l15 & 7)) << 3)];
                cj = mfma16(aq[kk], bk8, cj);
            }
            s[j] = cj;
        }
        // ---- additive mask + row max ----
        float tmax[4] = {-1e30f, -1e30f, -1e30f, -1e30f};
#pragma unroll
        for (int j = 0; j < 8; j++) {
            float mb = mk[j * 16 + l15];
#pragma unroll
            for (int rg = 0; rg < 4; rg++) {
                float v = s[j][rg] + mb;
                s[j][rg] = v;
                tmax[rg] = fmaxf(tmax[rg], v);
            }
        }
#pragma unroll
        for (int d = 1; d < 16; d <<= 1)
#pragma unroll
            for (int rg = 0; rg < 4; rg++) tmax[rg] = fmaxf(tmax[rg], __shfl_xor(tmax[rg], d));
        // ---- defer-max rescale (T13, THR=8) ----
        int need = 0;
#pragma unroll
        for (int rg = 0; rg < 4; rg++) need |= (tmax[rg] > mrun[rg] + 8.f) ? 1 : 0;
        if (__any(need)) {
#pragma unroll
            for (int rg = 0; rg < 4; rg++) {
                float mn = fmaxf(mrun[rg], tmax[rg]);
                float corr = __expf(mrun[rg] - mn);
                mrun[rg] = mn;
                lrun[rg] *= corr;
#pragma unroll
                for (int j6 = 0; j6 < 6; j6++) o[j6][rg] *= corr;
            }
        }
        // ---- P = exp(S - m), write to LDS, row sums ----
        float tsum[4] = {0.f, 0.f, 0.f, 0.f};
#pragma unroll
        for (int j = 0; j < 8; j++)
#pragma unroll
            for (int rg = 0; rg < 4; rg++) {
                float p = __expf(s[j][rg] - mrun[rg]);
                tsum[rg] += p;
                const int prow = l4 * 4 + rg;
                Pl[wid][prow * 128 + ((j * 16 + l15) ^ ((prow & 7) << 3))] = f2bf(p);
            }
#pragma unroll
        for (int d = 1; d < 16; d <<= 1)
#pragma unroll
            for (int rg = 0; rg < 4; rg++) tsum[rg] += __shfl_xor(tsum[rg], d);
#pragma unroll
        for (int rg = 0; rg < 4; rg++) lrun[rg] += tsum[rg];

        __syncthreads();   // V ready (vmcnt drain); P visible (own-wave anyway)

        // ---- O += P V ----
#pragma unroll
        for (int kk = 0; kk < 4; kk++) {
            bf16x8 ap = *(const bf16x8*)&Pl[wid][l15 * 128 + (((kk * 4 + l4) ^ (l15 & 7)) << 3)];
#pragma unroll
            for (int j6 = 0; j6 < 6; j6++) {
                const int d = j6 * 16 + l15;
                bf16x8 bv8 = *(const bf16x8*)&Vt[d * 128 + (((kk * 4 + l4) ^ (l15 & 7)) << 3)];
                o[j6] = mfma16(ap, bv8, o[j6]);
            }
        }
    }

    float inv[4];
#pragma unroll
    for (int rg = 0; rg < 4; rg++) inv[rg] = 1.f / lrun[rg];
    const size_t orow = (size_t)(qbase + (qblk << 7) + (wid << 4));
#pragma unroll
    for (int j6 = 0; j6 < 6; j6++)
#pragma unroll
        for (int rg = 0; rg < 4; rg++)
            attn[(orow + l4 * 4 + rg) * 768 + h * 96 + j6 * 16 + l15] = f2bf(o[j6][rg] * inv[rg]);
}

// ---------- LN1 + masked-pool accumulation ----------
__global__ __launch_bounds__(256) void k_ln_pool(const float* __restrict__ X,
                                                 const int* __restrict__ vmaskc,
                                                 const int* __restrict__ tmaskc,
                                                 const float* __restrict__ g,
                                                 const float* __restrict__ bb,
                                                 float* __restrict__ pooled,
                                                 int mvisL, int bg0) {
    __shared__ float pool[768];
    const int tid = threadIdx.x, wid = tid >> 6, lane = tid & 63;
    const int row0 = blockIdx.x << 5;
    const bool vis = row0 < mvisL;
    const int* mask = vis ? vmaskc : tmaskc;
    const int mbase = vis ? 0 : mvisL;
    const int bl = vis ? (row0 >> 10) : ((row0 - mvisL) >> 9);
    float* pout = pooled + (vis ? 0 : 12288) + (size_t)(bg0 + bl) * 768;

    float gv[12], bv2[12];
#pragma unroll
    for (int k = 0; k < 12; k++) { gv[k] = g[lane + k * 64]; bv2[k] = bb[lane + k * 64]; }
    float acc[12] = {};
    for (int rr = 0; rr < 8; ++rr) {
        const int row = row0 + (wid << 3) + rr;
        const float* x = X + (size_t)row * 768;
        float xs[12], sm = 0.f, s2 = 0.f;
#pragma unroll
        for (int k = 0; k < 12; k++) {
            float tv = x[lane + k * 64];
            xs[k] = tv; sm += tv; s2 += tv * tv;
        }
#pragma unroll
        for (int d = 1; d < 64; d <<= 1) { sm += __shfl_xor(sm, d); s2 += __shfl_xor(s2, d); }
        const float mean = sm * (1.f / 768.f);
        const float rstd = rsqrtf(s2 * (1.f / 768.f) - mean * mean + 1e-5f);
        const float mv = (float)mask[row - mbase];
#pragma unroll
        for (int k = 0; k < 12; k++) acc[k] += ((xs[k] - mean) * rstd * gv[k] + bv2[k]) * mv;
    }
    pool[tid] = 0.f; pool[tid + 256] = 0.f; pool[tid + 512] = 0.f;
    __syncthreads();
#pragma unroll
    for (int k = 0; k < 12; k++) atomicAdd(&pool[lane + k * 64], acc[k]);
    __syncthreads();
    atomicAdd(&pout[tid], pool[tid]);
    atomicAdd(&pout[tid + 256], pool[tid + 256]);
    atomicAdd(&pout[tid + 512], pool[tid + 512]);
}

// ---------- final ----------
__device__ __forceinline__ float blk_sum(float v, volatile float* tmp) {
#pragma unroll
    for (int d = 1; d < 64; d <<= 1) v += __shfl_xor(v, d);
    __syncthreads();
    if ((threadIdx.x & 63) == 0) tmp[threadIdx.x >> 6] = v;
    __syncthreads();
    return tmp[0] + tmp[1] + tmp[2] + tmp[3];
}

__global__ __launch_bounds__(256) void k_final(const float* __restrict__ pooled,
                                               const int* __restrict__ vmask,
                                               const int* __restrict__ tmask,
                                               const float* __restrict__ Wf,
                                               const float* __restrict__ bfv,
                                               const float* __restrict__ g2,
                                               const float* __restrict__ b2,
                                               float* __restrict__ out) {
    __shared__ float sh[1536];
    __shared__ float red[4];
    const int b = blockIdx.x, tid = threadIdx.x;
    float cv = 0.f, ct = 0.f;
    for (int i = tid; i < 1024; i += 256) cv += (float)vmask[(b << 10) + i];
    for (int i = tid; i < 512; i += 256) ct += (float)tmask[(b << 9) + i];
    cv = blk_sum(cv, red);
    ct = blk_sum(ct, red);
    const float iv = 1.f / cv, itv = 1.f / ct;
#pragma unroll
    for (int k = 0; k < 3; k++) {
        int j = tid + (k << 8);
        sh[j] = pooled[b * 768 + j] * iv;
        sh[768 + j] = pooled[12288 + b * 768 + j] * itv;
    }
    __syncthreads();
    float f0 = bfv[tid], f1 = bfv[tid + 256], f2 = bfv[tid + 512];
    for (int i = 0; i < 1536; i++) {
        const float pv = sh[i];
        const float* w = Wf + (size_t)i * 768;
        f0 += pv * w[tid];
        f1 += pv * w[tid + 256];
        f2 += pv * w[tid + 512];
    }
    float sm = blk_sum(f0 + f1 + f2, red);
    float s2 = blk_sum(f0 * f0 + f1 * f1 + f2 * f2, red);
    const float mean = sm * (1.f / 768.f);
    const float rstd = rsqrtf(s2 * (1.f / 768.f) - mean * mean + 1e-5f);
    out[b * 768 + tid] = (f0 - mean) * rstd * g2[tid] + b2[tid];
    out[b * 768 + tid + 256] = (f1 - mean) * rstd * g2[tid + 256] + b2[tid + 256];
    out[b * 768 + tid + 512] = (f2 - mean) * rstd * g2[tid + 512] + b2[tid + 512];
}

// ---------- host ----------
extern "C" void kernel_launch(void* const* d_in, const int* in_sizes, int n_in,
                              void* d_out, int out_size, void* d_ws, size_t ws_size,
                              hipStream_t stream) {
    (void)in_sizes; (void)n_in; (void)out_size;
    const float* vf = (const float*)d_in[0];
    const float* tf = (const float*)d_in[1];
    const int* vmask = (const int*)d_in[2];
    const int* tmask = (const int*)d_in[3];
    const float* Wq = (const float*)d_in[4];
    const float* bq = (const float*)d_in[5];
    const float* Wk = (const float*)d_in[6];
    const float* bk = (const float*)d_in[7];
    const float* Wv = (const float*)d_in[8];
    const float* bv = (const float*)d_in[9];
    const float* Wo = (const float*)d_in[10];
    const float* bo = (const float*)d_in[11];
    const float* g1 = (const float*)d_in[12];
    const float* b1 = (const float*)d_in[13];
    const float* Wf = (const float*)d_in[14];
    const float* bfv = (const float*)d_in[15];
    const float* g2 = (const float*)d_in[16];
    const float* b2 = (const float*)d_in[17];
    float* outp = (float*)d_out;

    // footprint = 4,826,112 + CH * (2,359,296 X + 7,077,888 QKV + 2,359,296 VtG)
    int CH = 16;
    while (CH > 1 && 4826112ull + (size_t)CH * 11796480ull > ws_size) CH >>= 1;
    const int NC = 16 / CH;
    const int Rtot = CH * 1536;

    char* ws = (char*)d_ws;
    u16*   wsW      = (u16*)(ws);
    u16*   wsWo     = (u16*)(ws + 3538944);
    float* wsBqkv   = (float*)(ws + 4718592);
    float* wsPooled = (float*)(ws + 4727808);
    u16*   wsX      = (u16*)(ws + 4826112);                 // [R][768] bf16 (reused: attn out)
    char*  qkvBase  = ws + 4826112 + (size_t)CH * 2359296;
    u16*   wsQKV    = (u16*)qkvBase;                         // [R][2304] bf16 (reused: Oproj f32)
    float* wsOproj  = (float*)qkvBase;
    u16*   wsVtG    = (u16*)(qkvBase + (size_t)CH * 7077888);// [768][R] bf16
    u16*   wsAttn   = wsX;

    k_transpose<<<dim3(144), dim3(256), 0, stream>>>(Wq, wsW, 768, 768);
    k_transpose<<<dim3(144), dim3(256), 0, stream>>>(Wk, wsW + 589824, 768, 768);
    k_transpose<<<dim3(144), dim3(256), 0, stream>>>(Wv, wsW + 1179648, 768, 768);
    k_transpose<<<dim3(144), dim3(256), 0, stream>>>(Wo, wsWo, 768, 768);
    k_bias<<<dim3(9), dim3(256), 0, stream>>>(bq, bk, bv, wsBqkv);
    k_zero<<<dim3(96), dim3(256), 0, stream>>>(wsPooled);

    for (int c = 0; c < NC; ++c) {
        const float* vfc = vf + (size_t)c * CH * 1024 * 768;
        const float* tfc = tf + (size_t)c * CH * 512 * 768;
        const int* vmc = vmask + c * CH * 1024;
        const int* tmc = tmask + c * CH * 512;

        k_cvt_x<<<dim3(CH * 1152), dim3(256), 0, stream>>>(vfc, tfc, wsX, CH * 196608);

        k_gemm<true, false><<<dim3(CH * 216), dim3(256), 0, stream>>>(
            wsX, wsW, wsBqkv, nullptr, nullptr, (void*)wsQKV, 2304, 768, 0);

        k_vtrans<<<dim3(CH * 288), dim3(256), 0, stream>>>(wsQKV, wsVtG, Rtot);

        k_attn<<<dim3(CH * 96), dim3(512), 0, stream>>>(
            wsQKV, wsVtG, vmc, tmc, wsAttn, CH, Rtot);

        k_gemm<false, true><<<dim3(CH * 72), dim3(256), 0, stream>>>(
            wsAttn, wsWo, bo, vfc, tfc, (void*)wsOproj, 768, 768, CH * 1024);

        k_ln_pool<<<dim3(CH * 48), dim3(256), 0, stream>>>(
            wsOproj, vmc, tmc, g1, b1, wsPooled, CH * 1024, c * CH);
    }

    k_final<<<dim3(16), dim3(256), 0, stream>>>(wsPooled, vmask, tmask, Wf, bfv, g2, b2, outp);
}

// Round 5
// 537.040 us; speedup vs baseline: 1.1354x; 1.0054x over previous
//
#include <hip/hip_runtime.h>

typedef __bf16 bf16x8 __attribute__((ext_vector_type(8)));
typedef float f32x4 __attribute__((ext_vector_type(4)));
typedef unsigned short u16;
typedef unsigned int u32;
typedef u16 u16x8 __attribute__((ext_vector_type(8)));
typedef u16 u16x4 __attribute__((ext_vector_type(4)));

// B=16, SV=1024, ST=512, D=768, H=8, DH=96. Chunked over CH batches,
// R = CH*1536 rows (CH*1024 visual then CH*512 text).

__device__ __forceinline__ u16 f2bf(float f) {
    u32 u = __builtin_bit_cast(u32, f);
    u32 r = u + 0x7FFFu + ((u >> 16) & 1u);
    return (u16)(r >> 16);
}

__device__ __forceinline__ f32x4 mfma16(bf16x8 a, bf16x8 b, f32x4 c) {
    return __builtin_amdgcn_mfma_f32_16x16x32_bf16(a, b, c, 0, 0, 0);
}

#define GLOAD_LDS16(g, l) __builtin_amdgcn_global_load_lds( \
    (__attribute__((address_space(1))) void*)(g), \
    (__attribute__((address_space(3))) void*)(l), 16, 0, 0)

// ---------- prep kernels ----------

__global__ __launch_bounds__(256) void k_cvt_x(const float* __restrict__ vf,
                                               const float* __restrict__ tf,
                                               u16* __restrict__ X, int nvis4) {
    int i = blockIdx.x * 256 + threadIdx.x;
    f32x4 v = (i < nvis4) ? ((const f32x4*)vf)[i] : ((const f32x4*)tf)[i - nvis4];
    u16x4 o = { f2bf(v[0]), f2bf(v[1]), f2bf(v[2]), f2bf(v[3]) };
    ((u16x4*)X)[i] = o;
}

// src f32 [K0][N0] -> dst bf16 [N0][K0]   (64x64 LDS tiles)
__global__ __launch_bounds__(256) void k_transpose(const float* __restrict__ src,
                                                   u16* __restrict__ dst,
                                                   int K0, int N0) {
    __shared__ float t[64][65];
    int ntx = N0 >> 6;
    int k0 = (blockIdx.x / ntx) << 6, n0 = (blockIdx.x % ntx) << 6;
    int c = threadIdx.x & 63, rr = threadIdx.x >> 6;
#pragma unroll
    for (int q = 0; q < 16; q++) {
        int r = q * 4 + rr;
        t[r][c] = src[(size_t)(k0 + r) * N0 + n0 + c];
    }
    __syncthreads();
#pragma unroll
    for (int q = 0; q < 16; q++) {
        int r = q * 4 + rr;
        dst[(size_t)(n0 + r) * K0 + k0 + c] = f2bf(t[c][r]);
    }
}

__global__ __launch_bounds__(256) void k_bias(const float* __restrict__ bq,
                                              const float* __restrict__ bk,
                                              const float* __restrict__ bv,
                                              float* __restrict__ bqkv) {
    int n = blockIdx.x * 256 + threadIdx.x;
    if (n < 2304) {
        const float* s = (n < 768) ? bq : ((n < 1536) ? bk : bv);
        int r = (n < 768) ? n : ((n < 1536) ? n - 768 : n - 1536);
        bqkv[n] = s[r];
    }
}

__global__ __launch_bounds__(256) void k_zero(float* __restrict__ p) {
    p[blockIdx.x * 256 + threadIdx.x] = 0.f;
}

// ---------- V global transpose: QKV V-cols [R][768] -> VtG [768][R] bf16 ----------
__global__ __launch_bounds__(256) void k_vtrans(const u16* __restrict__ qkv,
                                                u16* __restrict__ VtG, int Rtot) {
    __shared__ alignas(16) u16 t[64][72];
    const int kt = blockIdx.x / 12, dt = blockIdx.x % 12;
    const int k0 = kt << 6, d0 = dt << 6;
    const int tid = threadIdx.x;
#pragma unroll
    for (int it = 0; it < 2; it++) {
        int c = it * 256 + tid;
        int r = c >> 3, cc = c & 7;
        u16x8 v = *(const u16x8*)&qkv[(size_t)(k0 + r) * 2304 + 1536 + d0 + cc * 8];
        *(u16x8*)&t[r][cc * 8] = v;
    }
    __syncthreads();
#pragma unroll
    for (int it = 0; it < 2; it++) {
        int c = it * 256 + tid;
        int k8 = c & 7, d = c >> 3;
        u16x8 o;
#pragma unroll
        for (int e = 0; e < 8; e++) o[e] = t[k8 * 8 + e][d];
        *(u16x8*)&VtG[(size_t)(d0 + d) * Rtot + k0 + k8 * 8] = o;
    }
}

// ---------- GEMM: C[R][N] = A[R][K] * Bt[N][K]^T + bias (+residual) ----------
template <bool OUT_BF16, bool ADD_RES>
__global__ __launch_bounds__(256) void k_gemm(const u16* __restrict__ A,
                                              const u16* __restrict__ Bt,
                                              const float* __restrict__ bias,
                                              const float* __restrict__ resA,
                                              const float* __restrict__ resB,
                                              void* __restrict__ Cout,
                                              int Ndim, int Kdim, int mvisL) {
    __shared__ alignas(16) u16 sA[128 * 32];
    __shared__ alignas(16) u16 sB[128 * 32];
    const int tid = threadIdx.x, wid = tid >> 6, lane = tid & 63;
    const int ntiles = Ndim >> 7;
    const int mt = blockIdx.x / ntiles, nt = blockIdx.x - mt * ntiles;
    const int m0 = mt << 7, n0 = nt << 7;
    const int wm = wid >> 1, wn = wid & 1;
    f32x4 acc[4][4] = {};

    const int r0 = tid >> 2, p0 = tid & 3;
    const int r1 = 64 + (tid >> 2);
    const u16* ga0 = A + (size_t)(m0 + r0) * Kdim + p0 * 8;
    const u16* ga1 = A + (size_t)(m0 + r1) * Kdim + p0 * 8;
    const u16* gb0 = Bt + (size_t)(n0 + r0) * Kdim + p0 * 8;
    const u16* gb1 = Bt + (size_t)(n0 + r1) * Kdim + p0 * 8;
    u16* lA0 = sA + (wid * 64) * 8;
    u16* lA1 = sA + (256 + wid * 64) * 8;
    u16* lB0 = sB + (wid * 64) * 8;
    u16* lB1 = sB + (256 + wid * 64) * 8;

    const int arow = (wm << 6) + (lane & 15);
    const int brow = (wn << 6) + (lane & 15);
    const int kg = (lane >> 4) * 8;

    for (int kt = 0; kt < Kdim; kt += 32) {
        GLOAD_LDS16(ga0 + kt, lA0);
        GLOAD_LDS16(ga1 + kt, lA1);
        GLOAD_LDS16(gb0 + kt, lB0);
        GLOAD_LDS16(gb1 + kt, lB1);
        __syncthreads();
        bf16x8 av[4], bw[4];
#pragma unroll
        for (int i = 0; i < 4; i++) av[i] = *(const bf16x8*)&sA[(arow + i * 16) * 32 + kg];
#pragma unroll
        for (int j = 0; j < 4; j++) bw[j] = *(const bf16x8*)&sB[(brow + j * 16) * 32 + kg];
#pragma unroll
        for (int i = 0; i < 4; i++)
#pragma unroll
            for (int j = 0; j < 4; j++) acc[i][j] = mfma16(av[i], bw[j], acc[i][j]);
        __syncthreads();
    }

    const int col0 = n0 + (wn << 6) + (lane & 15);
    const int rowb = m0 + (wm << 6) + ((lane >> 4) << 2);
    float bvals[4];
#pragma unroll
    for (int j = 0; j < 4; j++) bvals[j] = bias[col0 + j * 16];
#pragma unroll
    for (int i = 0; i < 4; i++) {
#pragma unroll
        for (int rg = 0; rg < 4; rg++) {
            const int row = rowb + i * 16 + rg;
            const float* rp = nullptr;
            if constexpr (ADD_RES)
                rp = (row < mvisL) ? resA + (size_t)row * 768
                                   : resB + (size_t)(row - mvisL) * 768;
#pragma unroll
            for (int j = 0; j < 4; j++) {
                const int col = col0 + j * 16;
                float v = acc[i][j][rg] + bvals[j];
                if constexpr (ADD_RES) v += rp[col];
                if constexpr (OUT_BF16)
                    ((u16*)Cout)[(size_t)row * Ndim + col] = f2bf(v);
                else
                    ((float*)Cout)[(size_t)row * Ndim + col] = v;
            }
        }
    }
}

// ---------- fused cross-attention ----------
// One block per (b,h,direction): all q-tiles looped inside (serpentine k-order
// for L2 reuse), K/V double-buffered, ONE barrier per step, stage(next) issued
// right after the barrier so its latency hides under compute (2-phase pipeline).
__global__ __launch_bounds__(512) void k_attn(const u16* __restrict__ qkv,
                                              const u16* __restrict__ VtG,
                                              const int* __restrict__ vmaskc,
                                              const int* __restrict__ tmaskc,
                                              u16* __restrict__ attn, int CHn, int Rtot) {
    __shared__ alignas(16) u16 Kl[2][128 * 128];   // 64 KB
    __shared__ alignas(16) u16 Vt[2][96 * 128];    // 48 KB
    __shared__ alignas(16) u16 Pl[8][16 * 128];    // 32 KB
    __shared__ float mk[2][128];

    const int bx = blockIdx.x;
    int b, h, qbase, kbase, nqt, ntl;
    const int* mask;
    const int vcap = CHn * 8;
    if (bx < vcap) {   // visual queries attend to text
        b = bx >> 3; h = bx & 7;
        qbase = b << 10; kbase = (CHn << 10) + (b << 9);
        mask = tmaskc + (b << 9); nqt = 8; ntl = 2;   // ntile=4 (Sk=512)
    } else {           // text queries attend to visual
        const int bx2 = bx - vcap;
        b = bx2 >> 3; h = bx2 & 7;
        qbase = (CHn << 10) + (b << 9); kbase = b << 10;
        mask = vmaskc + (b << 10); nqt = 4; ntl = 3;  // ntile=8 (Sk=1024)
    }
    const int ntile = 1 << ntl;
    const int nsteps = nqt << ntl;
    const int tid = threadIdx.x, wid = tid >> 6, lane = tid & 63;
    const int l15 = lane & 15, l4 = lane >> 4;
    const float scale = 0.10206207261596577f;  // 1/sqrt(96)

    auto kt_of = [&](int s) {
        const int qt = s >> ntl, ktr = s & (ntile - 1);
        return (qt & 1) ? (ntile - 1 - ktr) : ktr;   // serpentine
    };
    auto stage = [&](int kt, int pb) {
#pragma unroll
        for (int it = 0; it < 4; ++it) {             // K tile: 2048 16B chunks
            const int cb = it * 512 + (wid << 6);
            const int c = cb + lane;
            const int r = c >> 4, s8 = c & 15;
            const int k8 = s8 ^ (r & 7);
            const u16* src = qkv + (size_t)(kbase + (kt << 7) + r) * 2304 + 768 + h * 96
                             + (k8 < 12 ? k8 * 8 : 0);
            GLOAD_LDS16(src, &Kl[pb][(size_t)cb * 8]);
        }
#pragma unroll
        for (int it = 0; it < 3; ++it) {             // V tile: 1536 16B chunks
            const int cb = it * 512 + (wid << 6);
            const int c = cb + lane;
            const int d = c >> 4, s8 = c & 15;
            const int k8 = s8 ^ (d & 7);
            const u16* src = VtG + (size_t)(h * 96 + d) * Rtot + kbase + (kt << 7) + k8 * 8;
            GLOAD_LDS16(src, &Vt[pb][(size_t)cb * 8]);
        }
        if (tid < 128) mk[pb][tid] = mask[(kt << 7) + tid] ? 0.f : -1e30f;
    };

    stage(kt_of(0), 0);
    int s = 0;
    for (int qt = 0; qt < nqt; ++qt) {
        const int qr = qbase + (qt << 7) + (wid << 4) + l15;
        bf16x8 aq[3];
#pragma unroll
        for (int kk = 0; kk < 3; kk++) {
            bf16x8 tq = *(const bf16x8*)&qkv[(size_t)qr * 2304 + h * 96 + kk * 32 + l4 * 8];
#pragma unroll
            for (int e = 0; e < 8; e++) tq[e] = (__bf16)((float)tq[e] * scale);
            aq[kk] = tq;
        }
        f32x4 o[6] = {};
        float mrun[4] = {-1e30f, -1e30f, -1e30f, -1e30f};
        float lrun[4] = {0.f, 0.f, 0.f, 0.f};

        for (int ktr = 0; ktr < ntile; ++ktr, ++s) {
            const int cur = s & 1;
            __syncthreads();                      // publish stage(cur); all reads of cur^1 done
            if (s + 1 < nsteps) stage(kt_of(s + 1), cur ^ 1);

            // ---- S = Q K^T ----
            f32x4 sc[8];
#pragma unroll
            for (int j = 0; j < 8; j++) {
                f32x4 cj = {0.f, 0.f, 0.f, 0.f};
#pragma unroll
                for (int kk = 0; kk < 3; kk++) {
                    const int r = j * 16 + l15;
                    bf16x8 bk8 = *(const bf16x8*)&Kl[cur][r * 128 + (((kk * 4 + l4) ^ (l15 & 7)) << 3)];
                    cj = mfma16(aq[kk], bk8, cj);
                }
                sc[j] = cj;
            }
            // ---- additive mask + row max ----
            float tmax[4] = {-1e30f, -1e30f, -1e30f, -1e30f};
#pragma unroll
            for (int j = 0; j < 8; j++) {
                float mb = mk[cur][j * 16 + l15];
#pragma unroll
                for (int rg = 0; rg < 4; rg++) {
                    float v = sc[j][rg] + mb;
                    sc[j][rg] = v;
                    tmax[rg] = fmaxf(tmax[rg], v);
                }
            }
#pragma unroll
            for (int d = 1; d < 16; d <<= 1)
#pragma unroll
                for (int rg = 0; rg < 4; rg++) tmax[rg] = fmaxf(tmax[rg], __shfl_xor(tmax[rg], d));
            // ---- defer-max rescale (THR=8) ----
            int need = 0;
#pragma unroll
            for (int rg = 0; rg < 4; rg++) need |= (tmax[rg] > mrun[rg] + 8.f) ? 1 : 0;
            if (__any(need)) {
#pragma unroll
                for (int rg = 0; rg < 4; rg++) {
                    float mn = fmaxf(mrun[rg], tmax[rg]);
                    float corr = __expf(mrun[rg] - mn);
                    mrun[rg] = mn;
                    lrun[rg] *= corr;
#pragma unroll
                    for (int j6 = 0; j6 < 6; j6++) o[j6][rg] *= corr;
                }
            }
            // ---- P = exp(S - m) -> Pl, row sums ----
            float tsum[4] = {0.f, 0.f, 0.f, 0.f};
#pragma unroll
            for (int j = 0; j < 8; j++)
#pragma unroll
                for (int rg = 0; rg < 4; rg++) {
                    float p = __expf(sc[j][rg] - mrun[rg]);
                    tsum[rg] += p;
                    const int prow = l4 * 4 + rg;
                    Pl[wid][prow * 128 + ((j * 16 + l15) ^ ((prow & 7) << 3))] = f2bf(p);
                }
#pragma unroll
            for (int d = 1; d < 16; d <<= 1)
#pragma unroll
                for (int rg = 0; rg < 4; rg++) tsum[rg] += __shfl_xor(tsum[rg], d);
#pragma unroll
            for (int rg = 0; rg < 4; rg++) lrun[rg] += tsum[rg];

            // ---- O += P V  (same-wave Pl RAW: DS in-order; Vt[cur] staged 1 step ahead) ----
#pragma unroll
            for (int kk = 0; kk < 4; kk++) {
                bf16x8 ap = *(const bf16x8*)&Pl[wid][l15 * 128 + (((kk * 4 + l4) ^ (l15 & 7)) << 3)];
#pragma unroll
                for (int j6 = 0; j6 < 6; j6++) {
                    const int d = j6 * 16 + l15;
                    bf16x8 bv8 = *(const bf16x8*)&Vt[cur][d * 128 + (((kk * 4 + l4) ^ (l15 & 7)) << 3)];
                    o[j6] = mfma16(ap, bv8, o[j6]);
                }
            }
        }

        float inv[4];
#pragma unroll
        for (int rg = 0; rg < 4; rg++) inv[rg] = 1.f / lrun[rg];
        const size_t orow = (size_t)(qbase + (qt << 7) + (wid << 4));
#pragma unroll
        for (int j6 = 0; j6 < 6; j6++)
#pragma unroll
            for (int rg = 0; rg < 4; rg++)
                attn[(orow + l4 * 4 + rg) * 768 + h * 96 + j6 * 16 + l15] =
                    f2bf(o[j6][rg] * inv[rg]);
    }
}

// ---------- LN1 + masked-pool accumulation ----------
__global__ __launch_bounds__(256) void k_ln_pool(const float* __restrict__ X,
                                                 const int* __restrict__ vmaskc,
                                                 const int* __restrict__ tmaskc,
                                                 const float* __restrict__ g,
                                                 const float* __restrict__ bb,
                                                 float* __restrict__ pooled,
                                                 int mvisL, int bg0) {
    __shared__ float pool[768];
    const int tid = threadIdx.x, wid = tid >> 6, lane = tid & 63;
    const int row0 = blockIdx.x << 5;
    const bool vis = row0 < mvisL;
    const int* mask = vis ? vmaskc : tmaskc;
    const int mbase = vis ? 0 : mvisL;
    const int bl = vis ? (row0 >> 10) : ((row0 - mvisL) >> 9);
    float* pout = pooled + (vis ? 0 : 12288) + (size_t)(bg0 + bl) * 768;

    float gv[12], bv2[12];
#pragma unroll
    for (int k = 0; k < 12; k++) { gv[k] = g[lane + k * 64]; bv2[k] = bb[lane + k * 64]; }
    float acc[12] = {};
    for (int rr = 0; rr < 8; ++rr) {
        const int row = row0 + (wid << 3) + rr;
        const float* x = X + (size_t)row * 768;
        float xs[12], sm = 0.f, s2 = 0.f;
#pragma unroll
        for (int k = 0; k < 12; k++) {
            float tv = x[lane + k * 64];
            xs[k] = tv; sm += tv; s2 += tv * tv;
        }
#pragma unroll
        for (int d = 1; d < 64; d <<= 1) { sm += __shfl_xor(sm, d); s2 += __shfl_xor(s2, d); }
        const float mean = sm * (1.f / 768.f);
        const float rstd = rsqrtf(s2 * (1.f / 768.f) - mean * mean + 1e-5f);
        const float mv = (float)mask[row - mbase];
#pragma unroll
        for (int k = 0; k < 12; k++) acc[k] += ((xs[k] - mean) * rstd * gv[k] + bv2[k]) * mv;
    }
    pool[tid] = 0.f; pool[tid + 256] = 0.f; pool[tid + 512] = 0.f;
    __syncthreads();
#pragma unroll
    for (int k = 0; k < 12; k++) atomicAdd(&pool[lane + k * 64], acc[k]);
    __syncthreads();
    atomicAdd(&pout[tid], pool[tid]);
    atomicAdd(&pout[tid + 256], pool[tid + 256]);
    atomicAdd(&pout[tid + 512], pool[tid + 512]);
}

// ---------- final ----------
__device__ __forceinline__ float blk_sum(float v, volatile float* tmp) {
#pragma unroll
    for (int d = 1; d < 64; d <<= 1) v += __shfl_xor(v, d);
    __syncthreads();
    if ((threadIdx.x & 63) == 0) tmp[threadIdx.x >> 6] = v;
    __syncthreads();
    return tmp[0] + tmp[1] + tmp[2] + tmp[3];
}

__global__ __launch_bounds__(256) void k_final(const float* __restrict__ pooled,
                                               const int* __restrict__ vmask,
                                               const int* __restrict__ tmask,
                                               const float* __restrict__ Wf,
                                               const float* __restrict__ bfv,
                                               const float* __restrict__ g2,
                                               const float* __restrict__ b2,
                                               float* __restrict__ out) {
    __shared__ float sh[1536];
    __shared__ float red[4];
    const int b = blockIdx.x, tid = threadIdx.x;
    float cv = 0.f, ct = 0.f;
    for (int i = tid; i < 1024; i += 256) cv += (float)vmask[(b << 10) + i];
    for (int i = tid; i < 512; i += 256) ct += (float)tmask[(b << 9) + i];
    cv = blk_sum(cv, red);
    ct = blk_sum(ct, red);
    const float iv = 1.f / cv, itv = 1.f / ct;
#pragma unroll
    for (int k = 0; k < 3; k++) {
        int j = tid + (k << 8);
        sh[j] = pooled[b * 768 + j] * iv;
        sh[768 + j] = pooled[12288 + b * 768 + j] * itv;
    }
    __syncthreads();
    float f0 = bfv[tid], f1 = bfv[tid + 256], f2 = bfv[tid + 512];
    for (int i = 0; i < 1536; i++) {
        const float pv = sh[i];
        const float* w = Wf + (size_t)i * 768;
        f0 += pv * w[tid];
        f1 += pv * w[tid + 256];
        f2 += pv * w[tid + 512];
    }
    float sm = blk_sum(f0 + f1 + f2, red);
    float s2 = blk_sum(f0 * f0 + f1 * f1 + f2 * f2, red);
    const float mean = sm * (1.f / 768.f);
    const float rstd = rsqrtf(s2 * (1.f / 768.f) - mean * mean + 1e-5f);
    out[b * 768 + tid] = (f0 - mean) * rstd * g2[tid] + b2[tid];
    out[b * 768 + tid + 256] = (f1 - mean) * rstd * g2[tid + 256] + b2[tid + 256];
    out[b * 768 + tid + 512] = (f2 - mean) * rstd * g2[tid + 512] + b2[tid + 512];
}

// ---------- host ----------
extern "C" void kernel_launch(void* const* d_in, const int* in_sizes, int n_in,
                              void* d_out, int out_size, void* d_ws, size_t ws_size,
                              hipStream_t stream) {
    (void)in_sizes; (void)n_in; (void)out_size;
    const float* vf = (const float*)d_in[0];
    const float* tf = (const float*)d_in[1];
    const int* vmask = (const int*)d_in[2];
    const int* tmask = (const int*)d_in[3];
    const float* Wq = (const float*)d_in[4];
    const float* bq = (const float*)d_in[5];
    const float* Wk = (const float*)d_in[6];
    const float* bk = (const float*)d_in[7];
    const float* Wv = (const float*)d_in[8];
    const float* bv = (const float*)d_in[9];
    const float* Wo = (const float*)d_in[10];
    const float* bo = (const float*)d_in[11];
    const float* g1 = (const float*)d_in[12];
    const float* b1 = (const float*)d_in[13];
    const float* Wf = (const float*)d_in[14];
    const float* bfv = (const float*)d_in[15];
    const float* g2 = (const float*)d_in[16];
    const float* b2 = (const float*)d_in[17];
    float* outp = (float*)d_out;

    // footprint = 4,826,112 + CH * (2,359,296 X + 7,077,888 QKV + 2,359,296 VtG)
    int CH = 16;
    while (CH > 1 && 4826112ull + (size_t)CH * 11796480ull > ws_size) CH >>= 1;
    const int NC = 16 / CH;
    const int Rtot = CH * 1536;

    char* ws = (char*)d_ws;
    u16*   wsW      = (u16*)(ws);
    u16*   wsWo     = (u16*)(ws + 3538944);
    float* wsBqkv   = (float*)(ws + 4718592);
    float* wsPooled = (float*)(ws + 4727808);
    u16*   wsX      = (u16*)(ws + 4826112);                 // [R][768] bf16 (reused: attn out)
    char*  qkvBase  = ws + 4826112 + (size_t)CH * 2359296;
    u16*   wsQKV    = (u16*)qkvBase;                         // [R][2304] bf16 (reused: Oproj f32)
    float* wsOproj  = (float*)qkvBase;
    u16*   wsVtG    = (u16*)(qkvBase + (size_t)CH * 7077888);// [768][R] bf16
    u16*   wsAttn   = wsX;

    k_transpose<<<dim3(144), dim3(256), 0, stream>>>(Wq, wsW, 768, 768);
    k_transpose<<<dim3(144), dim3(256), 0, stream>>>(Wk, wsW + 589824, 768, 768);
    k_transpose<<<dim3(144), dim3(256), 0, stream>>>(Wv, wsW + 1179648, 768, 768);
    k_transpose<<<dim3(144), dim3(256), 0, stream>>>(Wo, wsWo, 768, 768);
    k_bias<<<dim3(9), dim3(256), 0, stream>>>(bq, bk, bv, wsBqkv);
    k_zero<<<dim3(96), dim3(256), 0, stream>>>(wsPooled);

    for (int c = 0; c < NC; ++c) {
        const float* vfc = vf + (size_t)c * CH * 1024 * 768;
        const float* tfc = tf + (size_t)c * CH * 512 * 768;
        const int* vmc = vmask + c * CH * 1024;
        const int* tmc = tmask + c * CH * 512;

        k_cvt_x<<<dim3(CH * 1152), dim3(256), 0, stream>>>(vfc, tfc, wsX, CH * 196608);

        k_gemm<true, false><<<dim3(CH * 216), dim3(256), 0, stream>>>(
            wsX, wsW, wsBqkv, nullptr, nullptr, (void*)wsQKV, 2304, 768, 0);

        k_vtrans<<<dim3(CH * 288), dim3(256), 0, stream>>>(wsQKV, wsVtG, Rtot);

        k_attn<<<dim3(CH * 16), dim3(512), 0, stream>>>(
            wsQKV, wsVtG, vmc, tmc, wsAttn, CH, Rtot);

        k_gemm<false, true><<<dim3(CH * 72), dim3(256), 0, stream>>>(
            wsAttn, wsWo, bo, vfc, tfc, (void*)wsOproj, 768, 768, CH * 1024);

        k_ln_pool<<<dim3(CH * 48), dim3(256), 0, stream>>>(
            wsOproj, vmc, tmc, g1, b1, wsPooled, CH * 1024, c * CH);
    }

    k_final<<<dim3(16), dim3(256), 0, stream>>>(wsPooled, vmask, tmask, Wf, bfv, g2, b2, outp);
}

// Round 6
// 531.776 us; speedup vs baseline: 1.1467x; 1.0099x over previous
//
#include <hip/hip_runtime.h>

typedef __bf16 bf16x8 __attribute__((ext_vector_type(8)));
typedef float f32x4 __attribute__((ext_vector_type(4)));
typedef unsigned short u16;
typedef unsigned int u32;
typedef u16 u16x8 __attribute__((ext_vector_type(8)));
typedef u16 u16x4 __attribute__((ext_vector_type(4)));

// B=16, SV=1024, ST=512, D=768, H=8, DH=96. Chunked over CH batches,
// R = CH*1536 rows (CH*1024 visual then CH*512 text).

__device__ __forceinline__ u16 f2bf(float f) {
    u32 u = __builtin_bit_cast(u32, f);
    u32 r = u + 0x7FFFu + ((u >> 16) & 1u);
    return (u16)(r >> 16);
}

__device__ __forceinline__ f32x4 mfma16(bf16x8 a, bf16x8 b, f32x4 c) {
    return __builtin_amdgcn_mfma_f32_16x16x32_bf16(a, b, c, 0, 0, 0);
}

#define GLOAD_LDS16(g, l) __builtin_amdgcn_global_load_lds( \
    (__attribute__((address_space(1))) void*)(g), \
    (__attribute__((address_space(3))) void*)(l), 16, 0, 0)

// ---------- prep kernels ----------

__global__ __launch_bounds__(256) void k_cvt_x(const float* __restrict__ vf,
                                               const float* __restrict__ tf,
                                               u16* __restrict__ X, int nvis4) {
    int i = blockIdx.x * 256 + threadIdx.x;
    f32x4 v = (i < nvis4) ? ((const f32x4*)vf)[i] : ((const f32x4*)tf)[i - nvis4];
    u16x4 o = { f2bf(v[0]), f2bf(v[1]), f2bf(v[2]), f2bf(v[3]) };
    ((u16x4*)X)[i] = o;
}

// src f32 [K0][N0] -> dst bf16 [N0][K0]   (64x64 LDS tiles)
__global__ __launch_bounds__(256) void k_transpose(const float* __restrict__ src,
                                                   u16* __restrict__ dst,
                                                   int K0, int N0) {
    __shared__ float t[64][65];
    int ntx = N0 >> 6;
    int k0 = (blockIdx.x / ntx) << 6, n0 = (blockIdx.x % ntx) << 6;
    int c = threadIdx.x & 63, rr = threadIdx.x >> 6;
#pragma unroll
    for (int q = 0; q < 16; q++) {
        int r = q * 4 + rr;
        t[r][c] = src[(size_t)(k0 + r) * N0 + n0 + c];
    }
    __syncthreads();
#pragma unroll
    for (int q = 0; q < 16; q++) {
        int r = q * 4 + rr;
        dst[(size_t)(n0 + r) * K0 + k0 + c] = f2bf(t[c][r]);
    }
}

__global__ __launch_bounds__(256) void k_bias(const float* __restrict__ bq,
                                              const float* __restrict__ bk,
                                              const float* __restrict__ bv,
                                              float* __restrict__ bqkv) {
    int n = blockIdx.x * 256 + threadIdx.x;
    if (n < 2304) {
        const float* s = (n < 768) ? bq : ((n < 1536) ? bk : bv);
        int r = (n < 768) ? n : ((n < 1536) ? n - 768 : n - 1536);
        bqkv[n] = s[r];
    }
}

__global__ __launch_bounds__(256) void k_zero(float* __restrict__ p) {
    p[blockIdx.x * 256 + threadIdx.x] = 0.f;
}

// ---------- V global transpose: QKV V-cols [R][768] -> VtG [768][R] bf16 ----------
__global__ __launch_bounds__(256) void k_vtrans(const u16* __restrict__ qkv,
                                                u16* __restrict__ VtG, int Rtot) {
    __shared__ alignas(16) u16 t[64][72];
    const int kt = blockIdx.x / 12, dt = blockIdx.x % 12;
    const int k0 = kt << 6, d0 = dt << 6;
    const int tid = threadIdx.x;
#pragma unroll
    for (int it = 0; it < 2; it++) {
        int c = it * 256 + tid;
        int r = c >> 3, cc = c & 7;
        u16x8 v = *(const u16x8*)&qkv[(size_t)(k0 + r) * 2304 + 1536 + d0 + cc * 8];
        *(u16x8*)&t[r][cc * 8] = v;
    }
    __syncthreads();
#pragma unroll
    for (int it = 0; it < 2; it++) {
        int c = it * 256 + tid;
        int k8 = c & 7, d = c >> 3;
        u16x8 o;
#pragma unroll
        for (int e = 0; e < 8; e++) o[e] = t[k8 * 8 + e][d];
        *(u16x8*)&VtG[(size_t)(d0 + d) * Rtot + k0 + k8 * 8] = o;
    }
}

// ---------- GEMM: C[R][N] = A[R][K] * Bt[N][K]^T + bias (+residual) ----------
template <bool OUT_BF16, bool ADD_RES>
__global__ __launch_bounds__(256) void k_gemm(const u16* __restrict__ A,
                                              const u16* __restrict__ Bt,
                                              const float* __restrict__ bias,
                                              const float* __restrict__ resA,
                                              const float* __restrict__ resB,
                                              void* __restrict__ Cout,
                                              int Ndim, int Kdim, int mvisL) {
    __shared__ alignas(16) u16 sA[128 * 32];
    __shared__ alignas(16) u16 sB[128 * 32];
    const int tid = threadIdx.x, wid = tid >> 6, lane = tid & 63;
    const int ntiles = Ndim >> 7;
    const int mt = blockIdx.x / ntiles, nt = blockIdx.x - mt * ntiles;
    const int m0 = mt << 7, n0 = nt << 7;
    const int wm = wid >> 1, wn = wid & 1;
    f32x4 acc[4][4] = {};

    const int r0 = tid >> 2, p0 = tid & 3;
    const int r1 = 64 + (tid >> 2);
    const u16* ga0 = A + (size_t)(m0 + r0) * Kdim + p0 * 8;
    const u16* ga1 = A + (size_t)(m0 + r1) * Kdim + p0 * 8;
    const u16* gb0 = Bt + (size_t)(n0 + r0) * Kdim + p0 * 8;
    const u16* gb1 = Bt + (size_t)(n0 + r1) * Kdim + p0 * 8;
    u16* lA0 = sA + (wid * 64) * 8;
    u16* lA1 = sA + (256 + wid * 64) * 8;
    u16* lB0 = sB + (wid * 64) * 8;
    u16* lB1 = sB + (256 + wid * 64) * 8;

    const int arow = (wm << 6) + (lane & 15);
    const int brow = (wn << 6) + (lane & 15);
    const int kg = (lane >> 4) * 8;

    for (int kt = 0; kt < Kdim; kt += 32) {
        GLOAD_LDS16(ga0 + kt, lA0);
        GLOAD_LDS16(ga1 + kt, lA1);
        GLOAD_LDS16(gb0 + kt, lB0);
        GLOAD_LDS16(gb1 + kt, lB1);
        __syncthreads();
        bf16x8 av[4], bw[4];
#pragma unroll
        for (int i = 0; i < 4; i++) av[i] = *(const bf16x8*)&sA[(arow + i * 16) * 32 + kg];
#pragma unroll
        for (int j = 0; j < 4; j++) bw[j] = *(const bf16x8*)&sB[(brow + j * 16) * 32 + kg];
#pragma unroll
        for (int i = 0; i < 4; i++)
#pragma unroll
            for (int j = 0; j < 4; j++) acc[i][j] = mfma16(av[i], bw[j], acc[i][j]);
        __syncthreads();
    }

    const int col0 = n0 + (wn << 6) + (lane & 15);
    const int rowb = m0 + (wm << 6) + ((lane >> 4) << 2);
    float bvals[4];
#pragma unroll
    for (int j = 0; j < 4; j++) bvals[j] = bias[col0 + j * 16];
#pragma unroll
    for (int i = 0; i < 4; i++) {
#pragma unroll
        for (int rg = 0; rg < 4; rg++) {
            const int row = rowb + i * 16 + rg;
            const float* rp = nullptr;
            if constexpr (ADD_RES)
                rp = (row < mvisL) ? resA + (size_t)row * 768
                                   : resB + (size_t)(row - mvisL) * 768;
#pragma unroll
            for (int j = 0; j < 4; j++) {
                const int col = col0 + j * 16;
                float v = acc[i][j][rg] + bvals[j];
                if constexpr (ADD_RES) v += rp[col];
                if constexpr (OUT_BF16)
                    ((u16*)Cout)[(size_t)row * Ndim + col] = f2bf(v);
                else
                    ((float*)Cout)[(size_t)row * Ndim + col] = v;
            }
        }
    }
}

// ---------- fused cross-attention ----------
// One block per (b,h,direction). 256 q-rows per K/V pass (2 q-sets of 128,
// each wave owns 16+16 rows) -> staged K/V traffic halves vs 128-row passes.
// K/V double-buffered, one barrier per step; Pl time-shared between q-sets.
__global__ __launch_bounds__(512) void k_attn(const u16* __restrict__ qkv,
                                              const u16* __restrict__ VtG,
                                              const int* __restrict__ vmaskc,
                                              const int* __restrict__ tmaskc,
                                              u16* __restrict__ attn, int CHn, int Rtot) {
    __shared__ alignas(16) u16 Kl[2][128 * 128];   // 64 KB
    __shared__ alignas(16) u16 Vt[2][96 * 128];    // 48 KB
    __shared__ alignas(16) u16 Pl[8][16 * 128];    // 32 KB
    __shared__ float mk[2][128];

    const int bx = blockIdx.x;
    int b, h, qbase, kbase, nqt, ntl;
    const int* mask;
    const int vcap = CHn * 8;
    if (bx < vcap) {   // visual queries attend to text: 4 passes x 256 rows
        b = bx >> 3; h = bx & 7;
        qbase = b << 10; kbase = (CHn << 10) + (b << 9);
        mask = tmaskc + (b << 9); nqt = 4; ntl = 2;   // ntile=4 (Sk=512)
    } else {           // text queries attend to visual: 2 passes x 256 rows
        const int bx2 = bx - vcap;
        b = bx2 >> 3; h = bx2 & 7;
        qbase = (CHn << 10) + (b << 9); kbase = b << 10;
        mask = vmaskc + (b << 10); nqt = 2; ntl = 3;  // ntile=8 (Sk=1024)
    }
    const int ntile = 1 << ntl;
    const int nsteps = nqt << ntl;
    const int tid = threadIdx.x, wid = tid >> 6, lane = tid & 63;
    const int l15 = lane & 15, l4 = lane >> 4;
    const float scale = 0.10206207261596577f;  // 1/sqrt(96)

    auto kt_of = [&](int s) {
        const int qt = s >> ntl, ktr = s & (ntile - 1);
        return (qt & 1) ? (ntile - 1 - ktr) : ktr;   // serpentine
    };
    auto stage = [&](int kt, int pb) {
#pragma unroll
        for (int it = 0; it < 4; ++it) {             // K tile: 2048 16B chunks
            const int cb = it * 512 + (wid << 6);
            const int c = cb + lane;
            const int r = c >> 4, s8 = c & 15;
            const int k8 = s8 ^ (r & 7);
            const u16* src = qkv + (size_t)(kbase + (kt << 7) + r) * 2304 + 768 + h * 96
                             + (k8 < 12 ? k8 * 8 : 0);
            GLOAD_LDS16(src, &Kl[pb][(size_t)cb * 8]);
        }
#pragma unroll
        for (int it = 0; it < 3; ++it) {             // V tile: 1536 16B chunks
            const int cb = it * 512 + (wid << 6);
            const int c = cb + lane;
            const int d = c >> 4, s8 = c & 15;
            const int k8 = s8 ^ (d & 7);
            const u16* src = VtG + (size_t)(h * 96 + d) * Rtot + kbase + (kt << 7) + k8 * 8;
            GLOAD_LDS16(src, &Vt[pb][(size_t)cb * 8]);
        }
        if (tid < 128) mk[pb][tid] = mask[(kt << 7) + tid] ? 0.f : -1e30f;
    };

    stage(kt_of(0), 0);
    int s = 0;
    for (int qt = 0; qt < nqt; ++qt) {
        // wave's rows: qbase + qt*256 + wid*32 + qs*16 + l15
        bf16x8 aq[2][3];
#pragma unroll
        for (int qs = 0; qs < 2; ++qs) {
            const int qr = qbase + (qt << 8) + (wid << 5) + qs * 16 + l15;
#pragma unroll
            for (int kk = 0; kk < 3; kk++) {
                bf16x8 tq = *(const bf16x8*)&qkv[(size_t)qr * 2304 + h * 96 + kk * 32 + l4 * 8];
#pragma unroll
                for (int e = 0; e < 8; e++) tq[e] = (__bf16)((float)tq[e] * scale);
                aq[qs][kk] = tq;
            }
        }
        f32x4 o[2][6] = {};
        float mrun[2][4], lrun[2][4];
#pragma unroll
        for (int qs = 0; qs < 2; ++qs)
#pragma unroll
            for (int rg = 0; rg < 4; rg++) { mrun[qs][rg] = -1e30f; lrun[qs][rg] = 0.f; }

        for (int ktr = 0; ktr < ntile; ++ktr, ++s) {
            const int cur = s & 1;
            __syncthreads();                      // publish stage(cur); reads of cur^1 done
            if (s + 1 < nsteps) stage(kt_of(s + 1), cur ^ 1);

#pragma unroll
            for (int qs = 0; qs < 2; ++qs) {
                // ---- S = Q K^T ----
                f32x4 sc[8];
#pragma unroll
                for (int j = 0; j < 8; j++) {
                    f32x4 cj = {0.f, 0.f, 0.f, 0.f};
#pragma unroll
                    for (int kk = 0; kk < 3; kk++) {
                        const int r = j * 16 + l15;
                        bf16x8 bk8 = *(const bf16x8*)&Kl[cur][r * 128 + (((kk * 4 + l4) ^ (l15 & 7)) << 3)];
                        cj = mfma16(aq[qs][kk], bk8, cj);
                    }
                    sc[j] = cj;
                }
                // ---- additive mask + row max ----
                float tmax[4] = {-1e30f, -1e30f, -1e30f, -1e30f};
#pragma unroll
                for (int j = 0; j < 8; j++) {
                    float mb = mk[cur][j * 16 + l15];
#pragma unroll
                    for (int rg = 0; rg < 4; rg++) {
                        float v = sc[j][rg] + mb;
                        sc[j][rg] = v;
                        tmax[rg] = fmaxf(tmax[rg], v);
                    }
                }
#pragma unroll
                for (int d = 1; d < 16; d <<= 1)
#pragma unroll
                    for (int rg = 0; rg < 4; rg++)
                        tmax[rg] = fmaxf(tmax[rg], __shfl_xor(tmax[rg], d));
                // ---- defer-max rescale (THR=8) ----
                int need = 0;
#pragma unroll
                for (int rg = 0; rg < 4; rg++) need |= (tmax[rg] > mrun[qs][rg] + 8.f) ? 1 : 0;
                if (__any(need)) {
#pragma unroll
                    for (int rg = 0; rg < 4; rg++) {
                        float mn = fmaxf(mrun[qs][rg], tmax[rg]);
                        float corr = __expf(mrun[qs][rg] - mn);
                        mrun[qs][rg] = mn;
                        lrun[qs][rg] *= corr;
#pragma unroll
                        for (int j6 = 0; j6 < 6; j6++) o[qs][j6][rg] *= corr;
                    }
                }
                // ---- P = exp(S - m) -> Pl (time-shared), row sums ----
                float tsum[4] = {0.f, 0.f, 0.f, 0.f};
#pragma unroll
                for (int j = 0; j < 8; j++)
#pragma unroll
                    for (int rg = 0; rg < 4; rg++) {
                        float p = __expf(sc[j][rg] - mrun[qs][rg]);
                        tsum[rg] += p;
                        const int prow = l4 * 4 + rg;
                        Pl[wid][prow * 128 + ((j * 16 + l15) ^ ((prow & 7) << 3))] = f2bf(p);
                    }
#pragma unroll
                for (int d = 1; d < 16; d <<= 1)
#pragma unroll
                    for (int rg = 0; rg < 4; rg++) tsum[rg] += __shfl_xor(tsum[rg], d);
#pragma unroll
                for (int rg = 0; rg < 4; rg++) lrun[qs][rg] += tsum[rg];

                // ---- O += P V  (same-wave Pl RAW; Vt[cur] staged 1 step ahead) ----
#pragma unroll
                for (int kk = 0; kk < 4; kk++) {
                    bf16x8 ap = *(const bf16x8*)&Pl[wid][l15 * 128 + (((kk * 4 + l4) ^ (l15 & 7)) << 3)];
#pragma unroll
                    for (int j6 = 0; j6 < 6; j6++) {
                        const int d = j6 * 16 + l15;
                        bf16x8 bv8 = *(const bf16x8*)&Vt[cur][d * 128 + (((kk * 4 + l4) ^ (l15 & 7)) << 3)];
                        o[qs][j6] = mfma16(ap, bv8, o[qs][j6]);
                    }
                }
            }
        }

#pragma unroll
        for (int qs = 0; qs < 2; ++qs) {
            float inv[4];
#pragma unroll
            for (int rg = 0; rg < 4; rg++) inv[rg] = 1.f / lrun[qs][rg];
            const size_t orow = (size_t)(qbase + (qt << 8) + (wid << 5) + qs * 16);
#pragma unroll
            for (int j6 = 0; j6 < 6; j6++)
#pragma unroll
                for (int rg = 0; rg < 4; rg++)
                    attn[(orow + l4 * 4 + rg) * 768 + h * 96 + j6 * 16 + l15] =
                        f2bf(o[qs][j6][rg] * inv[qs == 0 ? rg : rg]);
        }
    }
}

// ---------- LN1 + masked-pool accumulation ----------
__global__ __launch_bounds__(256) void k_ln_pool(const float* __restrict__ X,
                                                 const int* __restrict__ vmaskc,
                                                 const int* __restrict__ tmaskc,
                                                 const float* __restrict__ g,
                                                 const float* __restrict__ bb,
                                                 float* __restrict__ pooled,
                                                 int mvisL, int bg0) {
    __shared__ float pool[768];
    const int tid = threadIdx.x, wid = tid >> 6, lane = tid & 63;
    const int row0 = blockIdx.x << 5;
    const bool vis = row0 < mvisL;
    const int* mask = vis ? vmaskc : tmaskc;
    const int mbase = vis ? 0 : mvisL;
    const int bl = vis ? (row0 >> 10) : ((row0 - mvisL) >> 9);
    float* pout = pooled + (vis ? 0 : 12288) + (size_t)(bg0 + bl) * 768;

    float gv[12], bv2[12];
#pragma unroll
    for (int k = 0; k < 12; k++) { gv[k] = g[lane + k * 64]; bv2[k] = bb[lane + k * 64]; }
    float acc[12] = {};
    for (int rr = 0; rr < 8; ++rr) {
        const int row = row0 + (wid << 3) + rr;
        const float* x = X + (size_t)row * 768;
        float xs[12], sm = 0.f, s2 = 0.f;
#pragma unroll
        for (int k = 0; k < 12; k++) {
            float tv = x[lane + k * 64];
            xs[k] = tv; sm += tv; s2 += tv * tv;
        }
#pragma unroll
        for (int d = 1; d < 64; d <<= 1) { sm += __shfl_xor(sm, d); s2 += __shfl_xor(s2, d); }
        const float mean = sm * (1.f / 768.f);
        const float rstd = rsqrtf(s2 * (1.f / 768.f) - mean * mean + 1e-5f);
        const float mv = (float)mask[row - mbase];
#pragma unroll
        for (int k = 0; k < 12; k++) acc[k] += ((xs[k] - mean) * rstd * gv[k] + bv2[k]) * mv;
    }
    pool[tid] = 0.f; pool[tid + 256] = 0.f; pool[tid + 512] = 0.f;
    __syncthreads();
#pragma unroll
    for (int k = 0; k < 12; k++) atomicAdd(&pool[lane + k * 64], acc[k]);
    __syncthreads();
    atomicAdd(&pout[tid], pool[tid]);
    atomicAdd(&pout[tid + 256], pool[tid + 256]);
    atomicAdd(&pout[tid + 512], pool[tid + 512]);
}

// ---------- final ----------
__device__ __forceinline__ float blk_sum(float v, volatile float* tmp) {
#pragma unroll
    for (int d = 1; d < 64; d <<= 1) v += __shfl_xor(v, d);
    __syncthreads();
    if ((threadIdx.x & 63) == 0) tmp[threadIdx.x >> 6] = v;
    __syncthreads();
    return tmp[0] + tmp[1] + tmp[2] + tmp[3];
}

__global__ __launch_bounds__(256) void k_final(const float* __restrict__ pooled,
                                               const int* __restrict__ vmask,
                                               const int* __restrict__ tmask,
                                               const float* __restrict__ Wf,
                                               const float* __restrict__ bfv,
                                               const float* __restrict__ g2,
                                               const float* __restrict__ b2,
                                               float* __restrict__ out) {
    __shared__ float sh[1536];
    __shared__ float red[4];
    const int b = blockIdx.x, tid = threadIdx.x;
    float cv = 0.f, ct = 0.f;
    for (int i = tid; i < 1024; i += 256) cv += (float)vmask[(b << 10) + i];
    for (int i = tid; i < 512; i += 256) ct += (float)tmask[(b << 9) + i];
    cv = blk_sum(cv, red);
    ct = blk_sum(ct, red);
    const float iv = 1.f / cv, itv = 1.f / ct;
#pragma unroll
    for (int k = 0; k < 3; k++) {
        int j = tid + (k << 8);
        sh[j] = pooled[b * 768 + j] * iv;
        sh[768 + j] = pooled[12288 + b * 768 + j] * itv;
    }
    __syncthreads();
    float f0 = bfv[tid], f1 = bfv[tid + 256], f2 = bfv[tid + 512];
    for (int i = 0; i < 1536; i++) {
        const float pv = sh[i];
        const float* w = Wf + (size_t)i * 768;
        f0 += pv * w[tid];
        f1 += pv * w[tid + 256];
        f2 += pv * w[tid + 512];
    }
    float sm = blk_sum(f0 + f1 + f2, red);
    float s2 = blk_sum(f0 * f0 + f1 * f1 + f2 * f2, red);
    const float mean = sm * (1.f / 768.f);
    const float rstd = rsqrtf(s2 * (1.f / 768.f) - mean * mean + 1e-5f);
    out[b * 768 + tid] = (f0 - mean) * rstd * g2[tid] + b2[tid];
    out[b * 768 + tid + 256] = (f1 - mean) * rstd * g2[tid + 256] + b2[tid + 256];
    out[b * 768 + tid + 512] = (f2 - mean) * rstd * g2[tid + 512] + b2[tid + 512];
}

// ---------- host ----------
extern "C" void kernel_launch(void* const* d_in, const int* in_sizes, int n_in,
                              void* d_out, int out_size, void* d_ws, size_t ws_size,
                              hipStream_t stream) {
    (void)in_sizes; (void)n_in; (void)out_size;
    const float* vf = (const float*)d_in[0];
    const float* tf = (const float*)d_in[1];
    const int* vmask = (const int*)d_in[2];
    const int* tmask = (const int*)d_in[3];
    const float* Wq = (const float*)d_in[4];
    const float* bq = (const float*)d_in[5];
    const float* Wk = (const float*)d_in[6];
    const float* bk = (const float*)d_in[7];
    const float* Wv = (const float*)d_in[8];
    const float* bv = (const float*)d_in[9];
    const float* Wo = (const float*)d_in[10];
    const float* bo = (const float*)d_in[11];
    const float* g1 = (const float*)d_in[12];
    const float* b1 = (const float*)d_in[13];
    const float* Wf = (const float*)d_in[14];
    const float* bfv = (const float*)d_in[15];
    const float* g2 = (const float*)d_in[16];
    const float* b2 = (const float*)d_in[17];
    float* outp = (float*)d_out;

    // footprint = 4,826,112 + CH * (2,359,296 X + 7,077,888 QKV + 2,359,296 VtG)
    int CH = 16;
    while (CH > 1 && 4826112ull + (size_t)CH * 11796480ull > ws_size) CH >>= 1;
    const int NC = 16 / CH;
    const int Rtot = CH * 1536;

    char* ws = (char*)d_ws;
    u16*   wsW      = (u16*)(ws);
    u16*   wsWo     = (u16*)(ws + 3538944);
    float* wsBqkv   = (float*)(ws + 4718592);
    float* wsPooled = (float*)(ws + 4727808);
    u16*   wsX      = (u16*)(ws + 4826112);                 // [R][768] bf16 (reused: attn out)
    char*  qkvBase  = ws + 4826112 + (size_t)CH * 2359296;
    u16*   wsQKV    = (u16*)qkvBase;                         // [R][2304] bf16 (reused: Oproj f32)
    float* wsOproj  = (float*)qkvBase;
    u16*   wsVtG    = (u16*)(qkvBase + (size_t)CH * 7077888);// [768][R] bf16
    u16*   wsAttn   = wsX;

    k_transpose<<<dim3(144), dim3(256), 0, stream>>>(Wq, wsW, 768, 768);
    k_transpose<<<dim3(144), dim3(256), 0, stream>>>(Wk, wsW + 589824, 768, 768);
    k_transpose<<<dim3(144), dim3(256), 0, stream>>>(Wv, wsW + 1179648, 768, 768);
    k_transpose<<<dim3(144), dim3(256), 0, stream>>>(Wo, wsWo, 768, 768);
    k_bias<<<dim3(9), dim3(256), 0, stream>>>(bq, bk, bv, wsBqkv);
    k_zero<<<dim3(96), dim3(256), 0, stream>>>(wsPooled);

    for (int c = 0; c < NC; ++c) {
        const float* vfc = vf + (size_t)c * CH * 1024 * 768;
        const float* tfc = tf + (size_t)c * CH * 512 * 768;
        const int* vmc = vmask + c * CH * 1024;
        const int* tmc = tmask + c * CH * 512;

        k_cvt_x<<<dim3(CH * 1152), dim3(256), 0, stream>>>(vfc, tfc, wsX, CH * 196608);

        k_gemm<true, false><<<dim3(CH * 216), dim3(256), 0, stream>>>(
            wsX, wsW, wsBqkv, nullptr, nullptr, (void*)wsQKV, 2304, 768, 0);

        k_vtrans<<<dim3(CH * 288), dim3(256), 0, stream>>>(wsQKV, wsVtG, Rtot);

        k_attn<<<dim3(CH * 16), dim3(512), 0, stream>>>(
            wsQKV, wsVtG, vmc, tmc, wsAttn, CH, Rtot);

        k_gemm<false, true><<<dim3(CH * 72), dim3(256), 0, stream>>>(
            wsAttn, wsWo, bo, vfc, tfc, (void*)wsOproj, 768, 768, CH * 1024);

        k_ln_pool<<<dim3(CH * 48), dim3(256), 0, stream>>>(
            wsOproj, vmc, tmc, g1, b1, wsPooled, CH * 1024, c * CH);
    }

    k_final<<<dim3(16), dim3(256), 0, stream>>>(wsPooled, vmask, tmask, Wf, bfv, g2, b2, outp);
}

// Round 7
// 510.202 us; speedup vs baseline: 1.1952x; 1.0423x over previous
//
#include <hip/hip_runtime.h>

typedef __bf16 bf16x8 __attribute__((ext_vector_type(8)));
typedef float f32x4 __attribute__((ext_vector_type(4)));
typedef unsigned short u16;
typedef unsigned int u32;
typedef u16 u16x8 __attribute__((ext_vector_type(8)));
typedef u16 u16x4 __attribute__((ext_vector_type(4)));

// B=16, SV=1024, ST=512, D=768, H=8, DH=96. Chunked over CH batches,
// R = CH*1536 rows (CH*1024 visual then CH*512 text).

__device__ __forceinline__ u16 f2bf(float f) {
    u32 u = __builtin_bit_cast(u32, f);
    u32 r = u + 0x7FFFu + ((u >> 16) & 1u);
    return (u16)(r >> 16);
}

__device__ __forceinline__ f32x4 mfma16(bf16x8 a, bf16x8 b, f32x4 c) {
    return __builtin_amdgcn_mfma_f32_16x16x32_bf16(a, b, c, 0, 0, 0);
}

#define GLOAD_LDS16(g, l) __builtin_amdgcn_global_load_lds( \
    (__attribute__((address_space(1))) void*)(g), \
    (__attribute__((address_space(3))) void*)(l), 16, 0, 0)

// ---------- prep kernels ----------

__global__ __launch_bounds__(256) void k_cvt_x(const float* __restrict__ vf,
                                               const float* __restrict__ tf,
                                               u16* __restrict__ X, int nvis4) {
    int i = blockIdx.x * 256 + threadIdx.x;
    f32x4 v = (i < nvis4) ? ((const f32x4*)vf)[i] : ((const f32x4*)tf)[i - nvis4];
    u16x4 o = { f2bf(v[0]), f2bf(v[1]), f2bf(v[2]), f2bf(v[3]) };
    ((u16x4*)X)[i] = o;
}

// src f32 [K0][N0] -> dst bf16 [N0][K0]   (64x64 LDS tiles)
__global__ __launch_bounds__(256) void k_transpose(const float* __restrict__ src,
                                                   u16* __restrict__ dst,
                                                   int K0, int N0) {
    __shared__ float t[64][65];
    int ntx = N0 >> 6;
    int k0 = (blockIdx.x / ntx) << 6, n0 = (blockIdx.x % ntx) << 6;
    int c = threadIdx.x & 63, rr = threadIdx.x >> 6;
#pragma unroll
    for (int q = 0; q < 16; q++) {
        int r = q * 4 + rr;
        t[r][c] = src[(size_t)(k0 + r) * N0 + n0 + c];
    }
    __syncthreads();
#pragma unroll
    for (int q = 0; q < 16; q++) {
        int r = q * 4 + rr;
        dst[(size_t)(n0 + r) * K0 + k0 + c] = f2bf(t[c][r]);
    }
}

__global__ __launch_bounds__(256) void k_bias(const float* __restrict__ bq,
                                              const float* __restrict__ bk,
                                              const float* __restrict__ bv,
                                              float* __restrict__ bqkv) {
    int n = blockIdx.x * 256 + threadIdx.x;
    if (n < 2304) {
        const float* s = (n < 768) ? bq : ((n < 1536) ? bk : bv);
        int r = (n < 768) ? n : ((n < 1536) ? n - 768 : n - 1536);
        bqkv[n] = s[r];
    }
}

__global__ __launch_bounds__(256) void k_zero(float* __restrict__ p) {
    p[blockIdx.x * 256 + threadIdx.x] = 0.f;
}

// ---------- V global transpose: QKV V-cols [R][768] -> VtG [768][R] bf16 ----------
__global__ __launch_bounds__(256) void k_vtrans(const u16* __restrict__ qkv,
                                                u16* __restrict__ VtG, int Rtot) {
    __shared__ alignas(16) u16 t[64][72];
    const int kt = blockIdx.x / 12, dt = blockIdx.x % 12;
    const int k0 = kt << 6, d0 = dt << 6;
    const int tid = threadIdx.x;
#pragma unroll
    for (int it = 0; it < 2; it++) {
        int c = it * 256 + tid;
        int r = c >> 3, cc = c & 7;
        u16x8 v = *(const u16x8*)&qkv[(size_t)(k0 + r) * 2304 + 1536 + d0 + cc * 8];
        *(u16x8*)&t[r][cc * 8] = v;
    }
    __syncthreads();
#pragma unroll
    for (int it = 0; it < 2; it++) {
        int c = it * 256 + tid;
        int k8 = c & 7, d = c >> 3;
        u16x8 o;
#pragma unroll
        for (int e = 0; e < 8; e++) o[e] = t[k8 * 8 + e][d];
        *(u16x8*)&VtG[(size_t)(d0 + d) * Rtot + k0 + k8 * 8] = o;
    }
}

// ---------- GEMM: C[R][N] = A[R][K] * Bt[N][K]^T + bias (+residual) ----------
// XCD-chunked blockIdx swizzle (grid always a multiple of 8): same-mt blocks
// stay on one XCD L2; full B panel fits the 4MB XCD L2.
template <bool OUT_BF16, bool ADD_RES>
__global__ __launch_bounds__(256) void k_gemm(const u16* __restrict__ A,
                                              const u16* __restrict__ Bt,
                                              const float* __restrict__ bias,
                                              const float* __restrict__ resA,
                                              const float* __restrict__ resB,
                                              void* __restrict__ Cout,
                                              int Ndim, int Kdim, int mvisL) {
    __shared__ alignas(16) u16 sA[128 * 32];
    __shared__ alignas(16) u16 sB[128 * 32];
    const int tid = threadIdx.x, wid = tid >> 6, lane = tid & 63;
    const int nwg = gridDim.x;
    const int wg = (blockIdx.x & 7) * (nwg >> 3) + (blockIdx.x >> 3);
    const int ntiles = Ndim >> 7;
    const int mt = wg / ntiles, nt = wg - mt * ntiles;
    const int m0 = mt << 7, n0 = nt << 7;
    const int wm = wid >> 1, wn = wid & 1;
    f32x4 acc[4][4] = {};

    const int r0 = tid >> 2, p0 = tid & 3;
    const int r1 = 64 + (tid >> 2);
    const u16* ga0 = A + (size_t)(m0 + r0) * Kdim + p0 * 8;
    const u16* ga1 = A + (size_t)(m0 + r1) * Kdim + p0 * 8;
    const u16* gb0 = Bt + (size_t)(n0 + r0) * Kdim + p0 * 8;
    const u16* gb1 = Bt + (size_t)(n0 + r1) * Kdim + p0 * 8;
    u16* lA0 = sA + (wid * 64) * 8;
    u16* lA1 = sA + (256 + wid * 64) * 8;
    u16* lB0 = sB + (wid * 64) * 8;
    u16* lB1 = sB + (256 + wid * 64) * 8;

    const int arow = (wm << 6) + (lane & 15);
    const int brow = (wn << 6) + (lane & 15);
    const int kg = (lane >> 4) * 8;

    for (int kt = 0; kt < Kdim; kt += 32) {
        GLOAD_LDS16(ga0 + kt, lA0);
        GLOAD_LDS16(ga1 + kt, lA1);
        GLOAD_LDS16(gb0 + kt, lB0);
        GLOAD_LDS16(gb1 + kt, lB1);
        __syncthreads();
        bf16x8 av[4], bw[4];
#pragma unroll
        for (int i = 0; i < 4; i++) av[i] = *(const bf16x8*)&sA[(arow + i * 16) * 32 + kg];
#pragma unroll
        for (int j = 0; j < 4; j++) bw[j] = *(const bf16x8*)&sB[(brow + j * 16) * 32 + kg];
#pragma unroll
        for (int i = 0; i < 4; i++)
#pragma unroll
            for (int j = 0; j < 4; j++) acc[i][j] = mfma16(av[i], bw[j], acc[i][j]);
        __syncthreads();
    }

    const int col0 = n0 + (wn << 6) + (lane & 15);
    const int rowb = m0 + (wm << 6) + ((lane >> 4) << 2);
    float bvals[4];
#pragma unroll
    for (int j = 0; j < 4; j++) bvals[j] = bias[col0 + j * 16];
#pragma unroll
    for (int i = 0; i < 4; i++) {
#pragma unroll
        for (int rg = 0; rg < 4; rg++) {
            const int row = rowb + i * 16 + rg;
            const float* rp = nullptr;
            if constexpr (ADD_RES)
                rp = (row < mvisL) ? resA + (size_t)row * 768
                                   : resB + (size_t)(row - mvisL) * 768;
#pragma unroll
            for (int j = 0; j < 4; j++) {
                const int col = col0 + j * 16;
                float v = acc[i][j][rg] + bvals[j];
                if constexpr (ADD_RES) v += rp[col];
                if constexpr (OUT_BF16)
                    ((u16*)Cout)[(size_t)row * Ndim + col] = f2bf(v);
                else
                    ((float*)Cout)[(size_t)row * Ndim + col] = v;
            }
        }
    }
}

// ---------- fused cross-attention ----------
// One block per (b,h,direction). 256 q-rows per K/V pass (2 q-sets of 128).
// j-outer QK^T: each K fragment is read from LDS ONCE and feeds both q-sets
// (halves the dominant LDS read stream). K/V double-buffered, one barrier/step.
__global__ __launch_bounds__(512) void k_attn(const u16* __restrict__ qkv,
                                              const u16* __restrict__ VtG,
                                              const int* __restrict__ vmaskc,
                                              const int* __restrict__ tmaskc,
                                              u16* __restrict__ attn, int CHn, int Rtot) {
    __shared__ alignas(16) u16 Kl[2][128 * 128];   // 64 KB
    __shared__ alignas(16) u16 Vt[2][96 * 128];    // 48 KB
    __shared__ alignas(16) u16 Pl[8][16 * 128];    // 32 KB
    __shared__ float mk[2][128];

    const int bx = blockIdx.x;
    int b, h, qbase, kbase, nqt, ntl;
    const int* mask;
    const int vcap = CHn * 8;
    if (bx < vcap) {   // visual queries attend to text: 4 passes x 256 rows
        b = bx >> 3; h = bx & 7;
        qbase = b << 10; kbase = (CHn << 10) + (b << 9);
        mask = tmaskc + (b << 9); nqt = 4; ntl = 2;   // ntile=4 (Sk=512)
    } else {           // text queries attend to visual: 2 passes x 256 rows
        const int bx2 = bx - vcap;
        b = bx2 >> 3; h = bx2 & 7;
        qbase = (CHn << 10) + (b << 9); kbase = b << 10;
        mask = vmaskc + (b << 10); nqt = 2; ntl = 3;  // ntile=8 (Sk=1024)
    }
    const int ntile = 1 << ntl;
    const int nsteps = nqt << ntl;
    const int tid = threadIdx.x, wid = tid >> 6, lane = tid & 63;
    const int l15 = lane & 15, l4 = lane >> 4;
    const float scale = 0.10206207261596577f;  // 1/sqrt(96)

    // loop-invariant swizzled k-offsets (bytes/u16 units within a 128-col row)
    int koff[4];
#pragma unroll
    for (int kk = 0; kk < 4; kk++) koff[kk] = ((kk * 4 + l4) ^ (l15 & 7)) << 3;

    auto kt_of = [&](int s) {
        const int qt = s >> ntl, ktr = s & (ntile - 1);
        return (qt & 1) ? (ntile - 1 - ktr) : ktr;   // serpentine
    };
    auto stage = [&](int kt, int pb) {
#pragma unroll
        for (int it = 0; it < 4; ++it) {             // K tile: 2048 16B chunks
            const int cb = it * 512 + (wid << 6);
            const int c = cb + lane;
            const int r = c >> 4, s8 = c & 15;
            const int k8 = s8 ^ (r & 7);
            const u16* src = qkv + (size_t)(kbase + (kt << 7) + r) * 2304 + 768 + h * 96
                             + (k8 < 12 ? k8 * 8 : 0);
            GLOAD_LDS16(src, &Kl[pb][(size_t)cb * 8]);
        }
#pragma unroll
        for (int it = 0; it < 3; ++it) {             // V tile: 1536 16B chunks
            const int cb = it * 512 + (wid << 6);
            const int c = cb + lane;
            const int d = c >> 4, s8 = c & 15;
            const int k8 = s8 ^ (d & 7);
            const u16* src = VtG + (size_t)(h * 96 + d) * Rtot + kbase + (kt << 7) + k8 * 8;
            GLOAD_LDS16(src, &Vt[pb][(size_t)cb * 8]);
        }
        if (tid < 128) mk[pb][tid] = mask[(kt << 7) + tid] ? 0.f : -1e30f;
    };

    stage(kt_of(0), 0);
    int s = 0;
    for (int qt = 0; qt < nqt; ++qt) {
        // wave's rows: qbase + qt*256 + wid*32 + qs*16 + l15
        bf16x8 aq[2][3];
#pragma unroll
        for (int qs = 0; qs < 2; ++qs) {
            const int qr = qbase + (qt << 8) + (wid << 5) + qs * 16 + l15;
#pragma unroll
            for (int kk = 0; kk < 3; kk++) {
                bf16x8 tq = *(const bf16x8*)&qkv[(size_t)qr * 2304 + h * 96 + kk * 32 + l4 * 8];
#pragma unroll
                for (int e = 0; e < 8; e++) tq[e] = (__bf16)((float)tq[e] * scale);
                aq[qs][kk] = tq;
            }
        }
        f32x4 o[2][6] = {};
        float mrun[2][4], lrun[2][4];
#pragma unroll
        for (int qs = 0; qs < 2; ++qs)
#pragma unroll
            for (int rg = 0; rg < 4; rg++) { mrun[qs][rg] = -1e30f; lrun[qs][rg] = 0.f; }

        for (int ktr = 0; ktr < ntile; ++ktr, ++s) {
            const int cur = s & 1;
            __syncthreads();                      // publish stage(cur); reads of cur^1 done
            if (s + 1 < nsteps) stage(kt_of(s + 1), cur ^ 1);

            // ---- S = Q K^T, j-outer: each K fragment read once, used by both q-sets ----
            f32x4 sc[2][8];
#pragma unroll
            for (int j = 0; j < 8; j++) {
                const int rbase = (j * 16 + l15) * 128;
                bf16x8 bk[3];
#pragma unroll
                for (int kk = 0; kk < 3; kk++)
                    bk[kk] = *(const bf16x8*)&Kl[cur][rbase + koff[kk]];
#pragma unroll
                for (int qs = 0; qs < 2; ++qs) {
                    f32x4 cj = {0.f, 0.f, 0.f, 0.f};
#pragma unroll
                    for (int kk = 0; kk < 3; kk++) cj = mfma16(aq[qs][kk], bk[kk], cj);
                    sc[qs][j] = cj;
                }
            }

#pragma unroll
            for (int qs = 0; qs < 2; ++qs) {
                // ---- additive mask + row max ----
                float tmax[4] = {-1e30f, -1e30f, -1e30f, -1e30f};
#pragma unroll
                for (int j = 0; j < 8; j++) {
                    float mb = mk[cur][j * 16 + l15];
#pragma unroll
                    for (int rg = 0; rg < 4; rg++) {
                        float v = sc[qs][j][rg] + mb;
                        sc[qs][j][rg] = v;
                        tmax[rg] = fmaxf(tmax[rg], v);
                    }
                }
#pragma unroll
                for (int d = 1; d < 16; d <<= 1)
#pragma unroll
                    for (int rg = 0; rg < 4; rg++)
                        tmax[rg] = fmaxf(tmax[rg], __shfl_xor(tmax[rg], d));
                // ---- defer-max rescale (THR=8) ----
                int need = 0;
#pragma unroll
                for (int rg = 0; rg < 4; rg++) need |= (tmax[rg] > mrun[qs][rg] + 8.f) ? 1 : 0;
                if (__any(need)) {
#pragma unroll
                    for (int rg = 0; rg < 4; rg++) {
                        float mn = fmaxf(mrun[qs][rg], tmax[rg]);
                        float corr = __expf(mrun[qs][rg] - mn);
                        mrun[qs][rg] = mn;
                        lrun[qs][rg] *= corr;
#pragma unroll
                        for (int j6 = 0; j6 < 6; j6++) o[qs][j6][rg] *= corr;
                    }
                }
                // ---- P = exp(S - m) -> Pl (time-shared), row sums ----
                float tsum[4] = {0.f, 0.f, 0.f, 0.f};
#pragma unroll
                for (int j = 0; j < 8; j++)
#pragma unroll
                    for (int rg = 0; rg < 4; rg++) {
                        float p = __expf(sc[qs][j][rg] - mrun[qs][rg]);
                        tsum[rg] += p;
                        const int prow = l4 * 4 + rg;
                        Pl[wid][prow * 128 + ((j * 16 + l15) ^ ((prow & 7) << 3))] = f2bf(p);
                    }
#pragma unroll
                for (int d = 1; d < 16; d <<= 1)
#pragma unroll
                    for (int rg = 0; rg < 4; rg++) tsum[rg] += __shfl_xor(tsum[rg], d);
#pragma unroll
                for (int rg = 0; rg < 4; rg++) lrun[qs][rg] += tsum[rg];

                // ---- O += P V  (same-wave Pl RAW; Vt[cur] staged 1 step ahead) ----
#pragma unroll
                for (int kk = 0; kk < 4; kk++) {
                    bf16x8 ap = *(const bf16x8*)&Pl[wid][l15 * 128 + koff[kk]];
#pragma unroll
                    for (int j6 = 0; j6 < 6; j6++) {
                        bf16x8 bv8 = *(const bf16x8*)&Vt[cur][(j6 * 16 + l15) * 128 + koff[kk]];
                        o[qs][j6] = mfma16(ap, bv8, o[qs][j6]);
                    }
                }
            }
        }

#pragma unroll
        for (int qs = 0; qs < 2; ++qs) {
            float inv[4];
#pragma unroll
            for (int rg = 0; rg < 4; rg++) inv[rg] = 1.f / lrun[qs][rg];
            const size_t orow = (size_t)(qbase + (qt << 8) + (wid << 5) + qs * 16);
#pragma unroll
            for (int j6 = 0; j6 < 6; j6++)
#pragma unroll
                for (int rg = 0; rg < 4; rg++)
                    attn[(orow + l4 * 4 + rg) * 768 + h * 96 + j6 * 16 + l15] =
                        f2bf(o[qs][j6][rg] * inv[rg]);
        }
    }
}

// ---------- LN1 + masked-pool accumulation ----------
__global__ __launch_bounds__(256) void k_ln_pool(const float* __restrict__ X,
                                                 const int* __restrict__ vmaskc,
                                                 const int* __restrict__ tmaskc,
                                                 const float* __restrict__ g,
                                                 const float* __restrict__ bb,
                                                 float* __restrict__ pooled,
                                                 int mvisL, int bg0) {
    __shared__ float pool[768];
    const int tid = threadIdx.x, wid = tid >> 6, lane = tid & 63;
    const int row0 = blockIdx.x << 5;
    const bool vis = row0 < mvisL;
    const int* mask = vis ? vmaskc : tmaskc;
    const int mbase = vis ? 0 : mvisL;
    const int bl = vis ? (row0 >> 10) : ((row0 - mvisL) >> 9);
    float* pout = pooled + (vis ? 0 : 12288) + (size_t)(bg0 + bl) * 768;

    float gv[12], bv2[12];
#pragma unroll
    for (int k = 0; k < 12; k++) { gv[k] = g[lane + k * 64]; bv2[k] = bb[lane + k * 64]; }
    float acc[12] = {};
    for (int rr = 0; rr < 8; ++rr) {
        const int row = row0 + (wid << 3) + rr;
        const float* x = X + (size_t)row * 768;
        float xs[12], sm = 0.f, s2 = 0.f;
#pragma unroll
        for (int k = 0; k < 12; k++) {
            float tv = x[lane + k * 64];
            xs[k] = tv; sm += tv; s2 += tv * tv;
        }
#pragma unroll
        for (int d = 1; d < 64; d <<= 1) { sm += __shfl_xor(sm, d); s2 += __shfl_xor(s2, d); }
        const float mean = sm * (1.f / 768.f);
        const float rstd = rsqrtf(s2 * (1.f / 768.f) - mean * mean + 1e-5f);
        const float mv = (float)mask[row - mbase];
#pragma unroll
        for (int k = 0; k < 12; k++) acc[k] += ((xs[k] - mean) * rstd * gv[k] + bv2[k]) * mv;
    }
    pool[tid] = 0.f; pool[tid + 256] = 0.f; pool[tid + 512] = 0.f;
    __syncthreads();
#pragma unroll
    for (int k = 0; k < 12; k++) atomicAdd(&pool[lane + k * 64], acc[k]);
    __syncthreads();
    atomicAdd(&pout[tid], pool[tid]);
    atomicAdd(&pout[tid + 256], pool[tid + 256]);
    atomicAdd(&pout[tid + 512], pool[tid + 512]);
}

// ---------- final ----------
__device__ __forceinline__ float blk_sum(float v, volatile float* tmp) {
#pragma unroll
    for (int d = 1; d < 64; d <<= 1) v += __shfl_xor(v, d);
    __syncthreads();
    if ((threadIdx.x & 63) == 0) tmp[threadIdx.x >> 6] = v;
    __syncthreads();
    return tmp[0] + tmp[1] + tmp[2] + tmp[3];
}

__global__ __launch_bounds__(256) void k_final(const float* __restrict__ pooled,
                                               const int* __restrict__ vmask,
                                               const int* __restrict__ tmask,
                                               const float* __restrict__ Wf,
                                               const float* __restrict__ bfv,
                                               const float* __restrict__ g2,
                                               const float* __restrict__ b2,
                                               float* __restrict__ out) {
    __shared__ float sh[1536];
    __shared__ float red[4];
    const int b = blockIdx.x, tid = threadIdx.x;
    float cv = 0.f, ct = 0.f;
    for (int i = tid; i < 1024; i += 256) cv += (float)vmask[(b << 10) + i];
    for (int i = tid; i < 512; i += 256) ct += (float)tmask[(b << 9) + i];
    cv = blk_sum(cv, red);
    ct = blk_sum(ct, red);
    const float iv = 1.f / cv, itv = 1.f / ct;
#pragma unroll
    for (int k = 0; k < 3; k++) {
        int j = tid + (k << 8);
        sh[j] = pooled[b * 768 + j] * iv;
        sh[768 + j] = pooled[12288 + b * 768 + j] * itv;
    }
    __syncthreads();
    float f0 = bfv[tid], f1 = bfv[tid + 256], f2 = bfv[tid + 512];
    for (int i = 0; i < 1536; i++) {
        const float pv = sh[i];
        const float* w = Wf + (size_t)i * 768;
        f0 += pv * w[tid];
        f1 += pv * w[tid + 256];
        f2 += pv * w[tid + 512];
    }
    float sm = blk_sum(f0 + f1 + f2, red);
    float s2 = blk_sum(f0 * f0 + f1 * f1 + f2 * f2, red);
    const float mean = sm * (1.f / 768.f);
    const float rstd = rsqrtf(s2 * (1.f / 768.f) - mean * mean + 1e-5f);
    out[b * 768 + tid] = (f0 - mean) * rstd * g2[tid] + b2[tid];
    out[b * 768 + tid + 256] = (f1 - mean) * rstd * g2[tid + 256] + b2[tid + 256];
    out[b * 768 + tid + 512] = (f2 - mean) * rstd * g2[tid + 512] + b2[tid + 512];
}

// ---------- host ----------
extern "C" void kernel_launch(void* const* d_in, const int* in_sizes, int n_in,
                              void* d_out, int out_size, void* d_ws, size_t ws_size,
                              hipStream_t stream) {
    (void)in_sizes; (void)n_in; (void)out_size;
    const float* vf = (const float*)d_in[0];
    const float* tf = (const float*)d_in[1];
    const int* vmask = (const int*)d_in[2];
    const int* tmask = (const int*)d_in[3];
    const float* Wq = (const float*)d_in[4];
    const float* bq = (const float*)d_in[5];
    const float* Wk = (const float*)d_in[6];
    const float* bk = (const float*)d_in[7];
    const float* Wv = (const float*)d_in[8];
    const float* bv = (const float*)d_in[9];
    const float* Wo = (const float*)d_in[10];
    const float* bo = (const float*)d_in[11];
    const float* g1 = (const float*)d_in[12];
    const float* b1 = (const float*)d_in[13];
    const float* Wf = (const float*)d_in[14];
    const float* bfv = (const float*)d_in[15];
    const float* g2 = (const float*)d_in[16];
    const float* b2 = (const float*)d_in[17];
    float* outp = (float*)d_out;

    // footprint = 4,826,112 + CH * (2,359,296 X + 7,077,888 QKV + 2,359,296 VtG)
    int CH = 16;
    while (CH > 1 && 4826112ull + (size_t)CH * 11796480ull > ws_size) CH >>= 1;
    const int NC = 16 / CH;
    const int Rtot = CH * 1536;

    char* ws = (char*)d_ws;
    u16*   wsW      = (u16*)(ws);
    u16*   wsWo     = (u16*)(ws + 3538944);
    float* wsBqkv   = (float*)(ws + 4718592);
    float* wsPooled = (float*)(ws + 4727808);
    u16*   wsX      = (u16*)(ws + 4826112);                 // [R][768] bf16 (reused: attn out)
    char*  qkvBase  = ws + 4826112 + (size_t)CH * 2359296;
    u16*   wsQKV    = (u16*)qkvBase;                         // [R][2304] bf16 (reused: Oproj f32)
    float* wsOproj  = (float*)qkvBase;
    u16*   wsVtG    = (u16*)(qkvBase + (size_t)CH * 7077888);// [768][R] bf16
    u16*   wsAttn   = wsX;

    k_transpose<<<dim3(144), dim3(256), 0, stream>>>(Wq, wsW, 768, 768);
    k_transpose<<<dim3(144), dim3(256), 0, stream>>>(Wk, wsW + 589824, 768, 768);
    k_transpose<<<dim3(144), dim3(256), 0, stream>>>(Wv, wsW + 1179648, 768, 768);
    k_transpose<<<dim3(144), dim3(256), 0, stream>>>(Wo, wsWo, 768, 768);
    k_bias<<<dim3(9), dim3(256), 0, stream>>>(bq, bk, bv, wsBqkv);
    k_zero<<<dim3(96), dim3(256), 0, stream>>>(wsPooled);

    for (int c = 0; c < NC; ++c) {
        const float* vfc = vf + (size_t)c * CH * 1024 * 768;
        const float* tfc = tf + (size_t)c * CH * 512 * 768;
        const int* vmc = vmask + c * CH * 1024;
        const int* tmc = tmask + c * CH * 512;

        k_cvt_x<<<dim3(CH * 1152), dim3(256), 0, stream>>>(vfc, tfc, wsX, CH * 196608);

        k_gemm<true, false><<<dim3(CH * 216), dim3(256), 0, stream>>>(
            wsX, wsW, wsBqkv, nullptr, nullptr, (void*)wsQKV, 2304, 768, 0);

        k_vtrans<<<dim3(CH * 288), dim3(256), 0, stream>>>(wsQKV, wsVtG, Rtot);

        k_attn<<<dim3(CH * 16), dim3(512), 0, stream>>>(
            wsQKV, wsVtG, vmc, tmc, wsAttn, CH, Rtot);

        k_gemm<false, true><<<dim3(CH * 72), dim3(256), 0, stream>>>(
            wsAttn, wsWo, bo, vfc, tfc, (void*)wsOproj, 768, 768, CH * 1024);

        k_ln_pool<<<dim3(CH * 48), dim3(256), 0, stream>>>(
            wsOproj, vmc, tmc, g1, b1, wsPooled, CH * 1024, c * CH);
    }

    k_final<<<dim3(16), dim3(256), 0, stream>>>(wsPooled, vmask, tmask, Wf, bfv, g2, b2, outp);
}